// Round 2
// 1717.886 us; speedup vs baseline: 4.8682x; 4.8682x over previous
//
#include <hip/hip_runtime.h>
#include <hip/hip_bf16.h>
#include <math.h>

#define BTOT 2048
#define VV 32000
#define HH 1024
#define INNER 2048
#define NA 17
#define MTOT (BTOT * NA)   // 34816 action-rows = 272 * 128

typedef __bf16 bf16;
typedef __bf16 bf16x8 __attribute__((ext_vector_type(8)));
typedef float f32x4 __attribute__((ext_vector_type(4)));

__device__ __forceinline__ f32x4 mfma16(bf16x8 a, bf16x8 b, f32x4 c) {
    return __builtin_amdgcn_mfma_f32_16x16x32_bf16(a, b, c, 0, 0, 0);
}

// async global->LDS, 16B per lane; LDS dest is wave-uniform base + lane*16
__device__ __forceinline__ void gload16(const void* g, void* l) {
    __builtin_amdgcn_global_load_lds(
        (const __attribute__((address_space(1))) unsigned int*)g,
        (__attribute__((address_space(3))) unsigned int*)l, 16, 0, 0);
}

__device__ __forceinline__ bool vi_better(float va, int ia, float vb, int ib) {
    return (va > vb) || (va == vb && ia < ib);
}

// ---------------------------------------------------------------------------
// Kernel 0: tiled transpose f32 -> bf16.  dst[c][r] = (bf16)src[r][c]
// ---------------------------------------------------------------------------
__global__ __launch_bounds__(256)
void transpose_to_bf16(const float* __restrict__ src, bf16* __restrict__ dst,
                       int R, int C)
{
    __shared__ float tile[32][33];
    const int bx = blockIdx.x * 32;
    const int by = blockIdx.y * 32;
    const int tx = threadIdx.x;
    const int ty = threadIdx.y;
#pragma unroll
    for (int i = 0; i < 32; i += 8)
        tile[ty + i][tx] = src[(size_t)(by + ty + i) * C + bx + tx];
    __syncthreads();
#pragma unroll
    for (int i = 0; i < 32; i += 8)
        dst[(size_t)(bx + ty + i) * R + by + tx] = (bf16)tile[tx][ty + i];
}

// ---------------------------------------------------------------------------
// Kernel 1: per-row top-16 + fused online log-sum-exp (single logits read)
// ---------------------------------------------------------------------------
__global__ __launch_bounds__(256)
void topk_lse_kernel(const float* __restrict__ logits,
                     const int* __restrict__ labels,
                     const unsigned char* __restrict__ future_valid,
                     int* __restrict__ actions,
                     int* __restrict__ amask,
                     float* __restrict__ lp,
                     int* __restrict__ rvalid,
                     int* __restrict__ validcount)
{
    const int r = blockIdx.x;
    const int t = threadIdx.x;
    const float* __restrict__ lrow = logits + (size_t)r * VV;

    __shared__ float cv[4096];
    __shared__ int   ci[4096];
    __shared__ float candv[256];
    __shared__ int   candi[256];
    __shared__ float s_topv[16];
    __shared__ int   s_topi[16];
    __shared__ int   s_wtid;
    __shared__ float s_red[256];

    float lv[16]; int li[16];
#pragma unroll
    for (int k = 0; k < 16; ++k) { lv[k] = -INFINITY; li[k] = 0x7fffffff; }
    float mrun = -INFINITY, srun = 0.f;

    const float4* __restrict__ lrow4 = (const float4*)lrow;
    for (int i = 0; i < 32; ++i) {
        int i4 = t + 256 * i;
        if (i4 < VV / 4) {
            float4 xv = lrow4[i4];
            float xs[4] = {xv.x, xv.y, xv.z, xv.w};
#pragma unroll
            for (int cc = 0; cc < 4; ++cc) {
                float x = xs[cc];
                int idx = i4 * 4 + cc;
                if (x > mrun) { srun = srun * __expf(mrun - x) + 1.f; mrun = x; }
                else          { srun += __expf(x - mrun); }
                if (vi_better(x, idx, lv[15], li[15])) {
#pragma unroll
                    for (int k = 15; k >= 1; --k) {
                        bool bk  = vi_better(x, idx, lv[k],   li[k]);
                        bool bk1 = vi_better(x, idx, lv[k-1], li[k-1]);
                        if (bk) {
                            if (bk1) { lv[k] = lv[k-1]; li[k] = li[k-1]; }
                            else     { lv[k] = x;       li[k] = idx;     }
                        }
                    }
                    if (vi_better(x, idx, lv[0], li[0])) { lv[0] = x; li[0] = idx; }
                }
            }
        }
    }
#pragma unroll
    for (int k = 0; k < 16; ++k) { cv[t*16+k] = lv[k]; ci[t*16+k] = li[k]; }
    candv[t] = lv[0]; candi[t] = li[0];
    __syncthreads();

    int cur = 0;
    for (int round = 0; round < 16; ++round) {
        if (t < 64) {
            float bv = -INFINITY; int bi = 0x7fffffff; int btid = -1;
#pragma unroll
            for (int k2 = 0; k2 < 4; ++k2) {
                int tid = t + 64 * k2;
                float v = candv[tid]; int ii = candi[tid];
                if (vi_better(v, ii, bv, bi)) { bv = v; bi = ii; btid = tid; }
            }
#pragma unroll
            for (int m2 = 1; m2 < 64; m2 <<= 1) {
                float ov = __shfl_xor(bv, m2, 64);
                int   oi = __shfl_xor(bi, m2, 64);
                int   ot = __shfl_xor(btid, m2, 64);
                if (vi_better(ov, oi, bv, bi)) { bv = ov; bi = oi; btid = ot; }
            }
            if (t == 0) { s_topv[round] = bv; s_topi[round] = bi; s_wtid = btid; }
        }
        __syncthreads();
        if (t == s_wtid) {
            ++cur;
            candv[t] = (cur < 16) ? cv[t*16+cur] : -INFINITY;
            candi[t] = (cur < 16) ? ci[t*16+cur] : 0x7fffffff;
        }
        __syncthreads();
    }

    float M = s_topv[0];
    s_red[t] = (mrun > -INFINITY) ? srun * __expf(mrun - M) : 0.f;
    __syncthreads();
    for (int s = 128; s > 0; s >>= 1) {
        if (t < s) s_red[t] += s_red[t+s];
        __syncthreads();
    }
    float lse = M + logf(s_red[0]);

    int lbl = labels[r];
    if (t < 16) {
        int ai = s_topi[t];
        actions[r*NA + t] = ai;
        amask[r*NA + t]   = 1;
        lp[r*NA + t]      = lrow[ai] - lse;
    } else if (t == 16) {
        bool dup = false;
#pragma unroll
        for (int k = 0; k < 16; ++k) dup = dup || (s_topi[k] == lbl);
        actions[r*NA + 16] = dup ? 0 : lbl;
        amask[r*NA + 16]   = dup ? 0 : 1;
        lp[r*NA + 16]      = dup ? 0.f : (lrow[lbl] - lse);
        bool valid = (lbl != -100) && (future_valid[r] != 0);
        rvalid[r] = valid ? 1 : 0;
        if (valid) atomicAdd(validcount, 1);
    }
}

// ---------------------------------------------------------------------------
// Kernel 2: build A (bf16): row m = r*17+a -> [hidden[r] | embed[action]]
// ---------------------------------------------------------------------------
__global__ __launch_bounds__(256)
void build_a_kernel(const float* __restrict__ hidden,
                    const float* __restrict__ embed,
                    const int* __restrict__ actions,
                    bf16* __restrict__ A, int m0)
{
    const int ml = blockIdx.x;
    const int m = m0 + ml;
    const int r = m / NA;
    const int a = m - r * NA;
    const int t = threadIdx.x;
    const float* src = (t < 128)
        ? hidden + (size_t)r * HH + t * 8
        : embed  + (size_t)actions[r*NA + a] * HH + (t - 128) * 8;
    float4 v0 = ((const float4*)src)[0];
    float4 v1 = ((const float4*)src)[1];
    bf16x8 o;
    o[0] = (bf16)v0.x; o[1] = (bf16)v0.y; o[2] = (bf16)v0.z; o[3] = (bf16)v0.w;
    o[4] = (bf16)v1.x; o[5] = (bf16)v1.y; o[6] = (bf16)v1.z; o[7] = (bf16)v1.w;
    *(bf16x8*)(A + (size_t)ml * INNER + t * 8) = o;
}

// ---------------------------------------------------------------------------
// Kernel 3: 128x128 MFMA GEMM (m97 structure: linear LDS + global_load_lds x16,
// 2-barrier K-loop, 4 waves each owning a 64x64 quadrant, 16x16x32 bf16 MFMA).
// C = A(Mx2048) * Bt(Nx2048)^T ; GELU epilogue -> bf16 out, or raw f32 out.
// K fixed = 2048.
// ---------------------------------------------------------------------------
template<bool GELU>
__global__ __launch_bounds__(256, 2)
void gemm128_kernel(const bf16* __restrict__ A,
                    const bf16* __restrict__ Bt,
                    const float* __restrict__ bias,
                    bf16* __restrict__ outB,
                    float* __restrict__ outF,
                    int N)
{
    const int nb = blockIdx.x;
    const int mb = blockIdx.y;
    const int t = threadIdx.x;
    const int w = t >> 6, lane = t & 63;
    const int q = lane >> 4, c = lane & 15;
    const int wr = w >> 1, wc = w & 1;

    __shared__ __align__(16) bf16 sA[128 * 32];
    __shared__ __align__(16) bf16 sB[128 * 32];

    // staging: element index within 128x32 tile; chunk=(w*2+j) covers 512 elems
    const int e0 = (w*2 + 0) * 512 + lane * 8;
    const int e1 = (w*2 + 1) * 512 + lane * 8;
    const bf16* gA0 = A  + (size_t)(mb*128 + (e0 >> 5)) * INNER + (e0 & 31);
    const bf16* gA1 = A  + (size_t)(mb*128 + (e1 >> 5)) * INNER + (e1 & 31);
    const bf16* gB0 = Bt + (size_t)(nb*128 + (e0 >> 5)) * INNER + (e0 & 31);
    const bf16* gB1 = Bt + (size_t)(nb*128 + (e1 >> 5)) * INNER + (e1 & 31);
    bf16* lA0 = sA + (w*2 + 0) * 512;   // wave-uniform LDS bases
    bf16* lA1 = sA + (w*2 + 1) * 512;
    bf16* lB0 = sB + (w*2 + 0) * 512;
    bf16* lB1 = sB + (w*2 + 1) * 512;

    const f32x4 z4 = {0.f, 0.f, 0.f, 0.f};
    f32x4 acc[4][4];
#pragma unroll
    for (int mt = 0; mt < 4; ++mt)
#pragma unroll
        for (int nt = 0; nt < 4; ++nt) acc[mt][nt] = z4;

#pragma unroll 1
    for (int k0 = 0; k0 < INNER; k0 += 32) {
        gload16(gA0 + k0, lA0);
        gload16(gA1 + k0, lA1);
        gload16(gB0 + k0, lB0);
        gload16(gB1 + k0, lB1);
        __syncthreads();   // drains vmcnt -> tiles visible

        bf16x8 af[4], bfr[4];
#pragma unroll
        for (int mt = 0; mt < 4; ++mt)
            af[mt] = *(const bf16x8*)&sA[(wr*64 + mt*16 + c) * 32 + q*8];
#pragma unroll
        for (int nt = 0; nt < 4; ++nt)
            bfr[nt] = *(const bf16x8*)&sB[(wc*64 + nt*16 + c) * 32 + q*8];
#pragma unroll
        for (int mt = 0; mt < 4; ++mt)
#pragma unroll
            for (int nt = 0; nt < 4; ++nt)
                acc[mt][nt] = mfma16(af[mt], bfr[nt], acc[mt][nt]);
        __syncthreads();   // all reads done before next stage overwrites
    }

    const int mrow = mb*128 + wr*64;
    const int ncol = nb*128 + wc*64;
#pragma unroll
    for (int nt = 0; nt < 4; ++nt) {
        const int n = ncol + nt*16 + c;
        float bb = 0.f;
        if constexpr (GELU) bb = bias[n];
#pragma unroll
        for (int mt = 0; mt < 4; ++mt) {
#pragma unroll
            for (int reg = 0; reg < 4; ++reg) {
                const int m = mrow + mt*16 + q*4 + reg;
                if constexpr (GELU) {
                    const float x = acc[mt][nt][reg] + bb;
                    const float g = 0.5f * x * (1.f + erff(x * 0.70710678118654752f));
                    outB[(size_t)m * N + n] = (bf16)g;
                } else {
                    outF[(size_t)m * N + n] = acc[mt][nt][reg];
                }
            }
        }
    }
}

// ---------------------------------------------------------------------------
// Kernel 4: per action-row: +b2, LayerNorm, cosine(action_repr, future) -> score
// ---------------------------------------------------------------------------
__global__ __launch_bounds__(256)
void ln_cos_kernel(const float* __restrict__ D,
                   const float* __restrict__ b2,
                   const float* __restrict__ ln_g,
                   const float* __restrict__ ln_b,
                   const float* __restrict__ future,
                   int m0,
                   float* __restrict__ scores)
{
    const int ml = blockIdx.x;
    const int m = m0 + ml;
    const int r = m / NA;
    const int t = threadIdx.x;
    const int w = t >> 6, lane = t & 63;
    __shared__ float s1[4], s2[4], s3[4], s4[4], s5[4];

    float4 d  = ((const float4*)(D + (size_t)ml * HH))[t];
    float4 bb = ((const float4*)b2)[t];
    d.x += bb.x; d.y += bb.y; d.z += bb.z; d.w += bb.w;

    float p1 = d.x + d.y + d.z + d.w;
    float p2 = d.x*d.x + d.y*d.y + d.z*d.z + d.w*d.w;
#pragma unroll
    for (int m2 = 1; m2 < 64; m2 <<= 1) {
        p1 += __shfl_xor(p1, m2, 64);
        p2 += __shfl_xor(p2, m2, 64);
    }
    if (lane == 0) { s1[w] = p1; s2[w] = p2; }
    __syncthreads();
    const float S1 = s1[0] + s1[1] + s1[2] + s1[3];
    const float S2 = s2[0] + s2[1] + s2[2] + s2[3];
    const float mu = S1 * (1.f / (float)HH);
    const float rstd = rsqrtf(S2 * (1.f / (float)HH) - mu*mu + 1e-5f);

    float4 g = ((const float4*)ln_g)[t];
    float4 b = ((const float4*)ln_b)[t];
    float4 f = ((const float4*)(future + (size_t)r * HH))[t];
    float4 ar;
    ar.x = (d.x - mu) * rstd * g.x + b.x;
    ar.y = (d.y - mu) * rstd * g.y + b.y;
    ar.z = (d.z - mu) * rstd * g.z + b.z;
    ar.w = (d.w - mu) * rstd * g.w + b.w;
    float paa = ar.x*ar.x + ar.y*ar.y + ar.z*ar.z + ar.w*ar.w;
    float paf = ar.x*f.x  + ar.y*f.y  + ar.z*f.z  + ar.w*f.w;
    float pff = f.x*f.x   + f.y*f.y   + f.z*f.z   + f.w*f.w;
#pragma unroll
    for (int m2 = 1; m2 < 64; m2 <<= 1) {
        paa += __shfl_xor(paa, m2, 64);
        paf += __shfl_xor(paf, m2, 64);
        pff += __shfl_xor(pff, m2, 64);
    }
    if (lane == 0) { s3[w] = paa; s4[w] = paf; s5[w] = pff; }
    __syncthreads();
    if (t == 0) {
        const float Saa = s3[0] + s3[1] + s3[2] + s3[3];
        const float Saf = s4[0] + s4[1] + s4[2] + s4[3];
        const float Sff = s5[0] + s5[1] + s5[2] + s5[3];
        const float anorm = fmaxf(sqrtf(Saa), 1e-12f);
        const float fnorm = fmaxf(sqrtf(Sff), 1e-12f);
        scores[m] = Saf / (anorm * fnorm);
    }
}

// ---------------------------------------------------------------------------
// Kernel 5: per token-row softmax over 17 scores + loss accumulation
// ---------------------------------------------------------------------------
__global__ __launch_bounds__(256)
void loss_kernel(const float* __restrict__ scores,
                 const int* __restrict__ amask,
                 const float* __restrict__ lp,
                 const int* __restrict__ rvalid,
                 const int* __restrict__ validcount,
                 float* __restrict__ out)
{
    const int r = blockIdx.x * blockDim.x + threadIdx.x;
    if (r >= BTOT) return;
    float sc[NA];
    float mx = -INFINITY;
#pragma unroll
    for (int a = 0; a < NA; ++a) {
        sc[a] = amask[r*NA + a] ? scores[r*NA + a] : -1e9f;
        mx = fmaxf(mx, sc[a]);
    }
    float ex[NA]; float ses = 0.f;
#pragma unroll
    for (int a = 0; a < NA; ++a) { ex[a] = __expf(sc[a] - mx); ses += ex[a]; }
    const int validr = rvalid[r];
    float acc = 0.f; int denom = 0;
#pragma unroll
    for (int a = 0; a < NA; ++a) {
        const int mk = amask[r*NA + a];
        const int mv = (mk && validr) ? 1 : 0;
        const float rw = (ex[a] / ses) * (float)mk;
        acc += rw * lp[r*NA + a] * (float)mv;
        denom += mv;
    }
    const float lossr = -acc / (float)(denom > 0 ? denom : 1) * (float)validr;
    atomicAdd(out, lossr / fmaxf((float)(*validcount), 1.f));
}

// ---------------------------------------------------------------------------
extern "C" void kernel_launch(void* const* d_in, const int* in_sizes, int n_in,
                              void* d_out, int out_size, void* d_ws, size_t ws_size,
                              hipStream_t stream)
{
    const float* logits        = (const float*)d_in[0];
    const float* hidden        = (const float*)d_in[1];
    const int*   labels        = (const int*)d_in[2];
    const float* future        = (const float*)d_in[3];
    const unsigned char* fvld  = (const unsigned char*)d_in[4];
    const float* embed         = (const float*)d_in[5];
    const float* W1f           = (const float*)d_in[6];
    const float* b1            = (const float*)d_in[7];
    const float* W2f           = (const float*)d_in[8];
    const float* b2            = (const float*)d_in[9];
    const float* ln_g          = (const float*)d_in[10];
    const float* ln_b          = (const float*)d_in[11];
    float* out = (float*)d_out;

    // ws layout: W1T | W2T | validcount | actions | amask | lp | rvalid |
    //            scores | slab{A (aliased by D f32)} | slab{Y}
    char* ws = (char*)d_ws;
    size_t off = 0;
    bf16* W1T = (bf16*)(ws + off); off += (size_t)INNER * INNER * 2;   // 8 MB
    bf16* W2T = (bf16*)(ws + off); off += (size_t)HH * INNER * 2;      // 4 MB
    int*   validcount = (int*)(ws + off);   off += 256;
    int*   actions    = (int*)(ws + off);   off += (size_t)MTOT * 4;
    int*   amask      = (int*)(ws + off);   off += (size_t)MTOT * 4;
    float* lp         = (float*)(ws + off); off += (size_t)MTOT * 4;
    int*   rvalid     = (int*)(ws + off);   off += (size_t)BTOT * 4;
    float* scores     = (float*)(ws + off); off += (size_t)MTOT * 4;
    off = (off + 255) & ~(size_t)255;

    // adaptive slab, strictly within ws_size:
    // per 128-row block: A bf16 (aliased later by D f32) 512KB + Y bf16 512KB
    size_t rem = (ws_size > off) ? (ws_size - off) : 0;
    long long cap_blocks = (long long)(rem / ((size_t)8192 * 128));
    int slab_blocks = (cap_blocks > (MTOT/128)) ? (MTOT/128) : (int)cap_blocks;
    if (slab_blocks < 1) slab_blocks = 1;   // requires ws_size >= ~14.1 MB
    const int slab_rows_max = slab_blocks * 128;

    bf16*  Abuf = (bf16*)(ws + off);
    float* Dbuf = (float*)Abuf;   // D aliases A (A dead after GEMM1 of same slab)
    bf16*  Ybuf = (bf16*)(ws + off + (size_t)slab_rows_max * 4096);

    (void)hipMemsetAsync(d_out, 0, sizeof(float), stream);
    (void)hipMemsetAsync(validcount, 0, 16, stream);

    // W1: [2048][2048] -> W1T[n][k]; W2: [2048][1024] -> W2T[j][k]
    transpose_to_bf16<<<dim3(INNER/32, INNER/32), dim3(32, 8), 0, stream>>>(W1f, W1T, INNER, INNER);
    transpose_to_bf16<<<dim3(HH/32,    INNER/32), dim3(32, 8), 0, stream>>>(W2f, W2T, INNER, HH);

    topk_lse_kernel<<<BTOT, 256, 0, stream>>>(logits, labels, fvld,
                                              actions, amask, lp, rvalid, validcount);

    for (int m0 = 0; m0 < MTOT; m0 += slab_rows_max) {
        const int rows = (MTOT - m0 < slab_rows_max) ? (MTOT - m0) : slab_rows_max;
        const int nbm = rows / 128;
        build_a_kernel<<<rows, 256, 0, stream>>>(hidden, embed, actions, Abuf, m0);
        gemm128_kernel<true ><<<dim3(INNER/128, nbm), 256, 0, stream>>>(
            Abuf, W1T, b1, Ybuf, nullptr, INNER);
        gemm128_kernel<false><<<dim3(HH/128, nbm), 256, 0, stream>>>(
            Ybuf, W2T, nullptr, nullptr, Dbuf, HH);
        ln_cos_kernel<<<rows, 256, 0, stream>>>(Dbuf, b2, ln_g, ln_b, future, m0, scores);
    }

    loss_kernel<<<(BTOT + 255) / 256, 256, 0, stream>>>(scores, amask, lp,
                                                        rvalid, validcount, out);
}

// Round 3
// 1203.710 us; speedup vs baseline: 6.9477x; 1.4272x over previous
//
#include <hip/hip_runtime.h>
#include <hip/hip_bf16.h>
#include <math.h>

#define BTOT 2048
#define VV 32000
#define HH 1024
#define INNER 2048
#define NA 17
#define MTOT (BTOT * NA)   // 34816 action-rows = 272 * 128
#define CAP 1088           // candidate buffer (provable worst case <= 1024)

typedef __bf16 bf16;
typedef __bf16 bf16x8 __attribute__((ext_vector_type(8)));
typedef float f32x4 __attribute__((ext_vector_type(4)));

__device__ __forceinline__ f32x4 mfma16(bf16x8 a, bf16x8 b, f32x4 c) {
    return __builtin_amdgcn_mfma_f32_16x16x32_bf16(a, b, c, 0, 0, 0);
}

// async global->LDS, 16B per lane; LDS dest is wave-uniform base + lane*16
__device__ __forceinline__ void gload16(const void* g, void* l) {
    __builtin_amdgcn_global_load_lds(
        (const __attribute__((address_space(1))) unsigned int*)g,
        (__attribute__((address_space(3))) unsigned int*)l, 16, 0, 0);
}

__device__ __forceinline__ bool vi_better(float va, int ia, float vb, int ib) {
    // jax.lax.top_k order: larger value first; ties -> smaller index first
    return (va > vb) || (va == vb && ia < ib);
}

// ---------------------------------------------------------------------------
// Kernel 0: tiled transpose f32 -> bf16.  dst[c][r] = (bf16)src[r][c]
// ---------------------------------------------------------------------------
__global__ __launch_bounds__(256)
void transpose_to_bf16(const float* __restrict__ src, bf16* __restrict__ dst,
                       int R, int C)
{
    __shared__ float tile[32][33];
    const int bx = blockIdx.x * 32;
    const int by = blockIdx.y * 32;
    const int tx = threadIdx.x;
    const int ty = threadIdx.y;
#pragma unroll
    for (int i = 0; i < 32; i += 8)
        tile[ty + i][tx] = src[(size_t)(by + ty + i) * C + bx + tx];
    __syncthreads();
#pragma unroll
    for (int i = 0; i < 32; i += 8)
        dst[(size_t)(bx + ty + i) * R + by + tx] = (bf16)tile[tx][ty + i];
}

// ---------------------------------------------------------------------------
// Kernel 1: per-row top-16 + LSE, two-pass threshold select.
// Pass 1: per-thread top-2 (branchless) -> 512 candidates -> threshold T =
// 16th best (lex).  Provably: T <= v16 and #{x >= T} <= 1024.
// Pass 2 (L2/L3-warm): branchless sum exp(x-M) + collect x >= T into LDS.
// Final: exact top-16 from collected buffer.
// ---------------------------------------------------------------------------
__global__ __launch_bounds__(256)
void topk_lse_kernel(const float* __restrict__ logits,
                     const int* __restrict__ labels,
                     const unsigned char* __restrict__ future_valid,
                     int* __restrict__ actions,
                     int* __restrict__ amask,
                     float* __restrict__ lp,
                     int* __restrict__ rvalid,
                     int* __restrict__ validcount)
{
    const int r = blockIdx.x;
    const int t = threadIdx.x;
    const float* __restrict__ lrow = logits + (size_t)r * VV;

    __shared__ float s_cv[CAP];
    __shared__ int   s_ci[CAP];
    __shared__ float candv[256];
    __shared__ int   candi[256];
    __shared__ float s_topv[16];
    __shared__ int   s_topi[16];
    __shared__ int   s_wtid;
    __shared__ int   s_cnt;
    __shared__ float s_redv[256];
    __shared__ int   s_redi[256];
    __shared__ int   s_redp[256];

    // ---- pass 1: per-thread top-2, value order (scan is ascending idx) ----
    float m1 = -INFINITY, m2 = -INFINITY;
    int   i1 = 0x7fffffff, i2 = 0x7fffffff;
    const float4* __restrict__ lrow4 = (const float4*)lrow;
    for (int i = 0; i < 32; ++i) {
        int i4 = t + 256 * i;
        if (i4 < VV / 4) {
            float4 xv = lrow4[i4];
            float xs[4] = {xv.x, xv.y, xv.z, xv.w};
#pragma unroll
            for (int cc = 0; cc < 4; ++cc) {
                float x = xs[cc];
                int idx = i4 * 4 + cc;
                bool b1 = x > m1;
                bool b2 = x > m2;
                float nm2 = b1 ? m1 : (b2 ? x : m2);
                int   ni2 = b1 ? i1 : (b2 ? idx : i2);
                m1 = b1 ? x : m1;
                i1 = b1 ? idx : i1;
                m2 = nm2; i2 = ni2;
            }
        }
    }
    candv[t] = m1; candi[t] = i1;
    if (t == 0) s_cnt = 0;
    __syncthreads();

    // ---- extraction over 512 candidates: 16 rounds -> T = 16th (lex) ----
    int cur = 0;
    for (int round = 0; round < 16; ++round) {
        if (t < 64) {
            float bv = -INFINITY; int bi = 0x7fffffff; int btid = -1;
#pragma unroll
            for (int k2 = 0; k2 < 4; ++k2) {
                int tid = t + 64 * k2;
                float v = candv[tid]; int ii = candi[tid];
                if (vi_better(v, ii, bv, bi)) { bv = v; bi = ii; btid = tid; }
            }
#pragma unroll
            for (int ms = 1; ms < 64; ms <<= 1) {
                float ov = __shfl_xor(bv, ms, 64);
                int   oi = __shfl_xor(bi, ms, 64);
                int   ot = __shfl_xor(btid, ms, 64);
                if (vi_better(ov, oi, bv, bi)) { bv = ov; bi = oi; btid = ot; }
            }
            if (t == 0) { s_topv[round] = bv; s_topi[round] = bi; s_wtid = btid; }
        }
        __syncthreads();
        if (t == s_wtid) {
            ++cur;
            candv[t] = (cur < 2) ? m2 : -INFINITY;
            candi[t] = (cur < 2) ? i2 : 0x7fffffff;
        }
        __syncthreads();
    }

    const float M  = s_topv[0];    // global row max
    const float Tv = s_topv[15];   // threshold (lex)
    const int   Ti = s_topi[15];

    // ---- pass 2: LSE sum (branchless) + candidate collection ----
    float lsum = 0.f;
    for (int i = 0; i < 32; ++i) {
        int i4 = t + 256 * i;
        if (i4 < VV / 4) {
            float4 xv = lrow4[i4];
            float xs[4] = {xv.x, xv.y, xv.z, xv.w};
#pragma unroll
            for (int cc = 0; cc < 4; ++cc) {
                float x = xs[cc];
                int idx = i4 * 4 + cc;
                lsum += __expf(x - M);
                if (!vi_better(Tv, Ti, x, idx)) {   // (x,idx) >= (Tv,Ti) lex
                    int p = atomicAdd(&s_cnt, 1);
                    if (p < CAP) { s_cv[p] = x; s_ci[p] = idx; }
                }
            }
        }
    }
    s_redv[t] = lsum;
    __syncthreads();
    for (int s = 128; s > 0; s >>= 1) {
        if (t < s) s_redv[t] += s_redv[t + s];
        __syncthreads();
    }
    const float lse = M + logf(s_redv[0]);
    int C = s_cnt; if (C > CAP) C = CAP;
    __syncthreads();   // everyone has read s_redv[0]/s_cnt before reuse

    // ---- final exact top-16 over collected candidates ----
    for (int round = 0; round < 16; ++round) {
        float bv = -INFINITY; int bi = 0x7fffffff; int bp = -1;
        for (int j = t; j < C; j += 256) {
            float v = s_cv[j]; int ii = s_ci[j];
            if (vi_better(v, ii, bv, bi)) { bv = v; bi = ii; bp = j; }
        }
        s_redv[t] = bv; s_redi[t] = bi; s_redp[t] = bp;
        __syncthreads();
        if (t < 64) {
#pragma unroll
            for (int k2 = 1; k2 < 4; ++k2) {
                float v = s_redv[t + 64*k2]; int ii = s_redi[t + 64*k2];
                int pp = s_redp[t + 64*k2];
                if (vi_better(v, ii, bv, bi)) { bv = v; bi = ii; bp = pp; }
            }
#pragma unroll
            for (int ms = 1; ms < 64; ms <<= 1) {
                float ov = __shfl_xor(bv, ms, 64);
                int   oi = __shfl_xor(bi, ms, 64);
                int   op = __shfl_xor(bp, ms, 64);
                if (vi_better(ov, oi, bv, bi)) { bv = ov; bi = oi; bp = op; }
            }
            if (t == 0) {
                s_topv[round] = bv; s_topi[round] = bi;
                if (bp >= 0) { s_cv[bp] = -INFINITY; s_ci[bp] = 0x7fffffff; }
            }
        }
        __syncthreads();
    }

    // ---- epilogue (unchanged semantics) ----
    int lbl = labels[r];
    if (t < 16) {
        actions[r*NA + t] = s_topi[t];
        amask[r*NA + t]   = 1;
        lp[r*NA + t]      = s_topv[t] - lse;
    } else if (t == 16) {
        bool dup = false;
#pragma unroll
        for (int k = 0; k < 16; ++k) dup = dup || (s_topi[k] == lbl);
        actions[r*NA + 16] = dup ? 0 : lbl;
        amask[r*NA + 16]   = dup ? 0 : 1;
        lp[r*NA + 16]      = dup ? 0.f : (lrow[lbl] - lse);
        bool valid = (lbl != -100) && (future_valid[r] != 0);
        rvalid[r] = valid ? 1 : 0;
        if (valid) atomicAdd(validcount, 1);
    }
}

// ---------------------------------------------------------------------------
// Kernel 2: build A (bf16): row m = r*17+a -> [hidden[r] | embed[action]]
// ---------------------------------------------------------------------------
__global__ __launch_bounds__(256)
void build_a_kernel(const float* __restrict__ hidden,
                    const float* __restrict__ embed,
                    const int* __restrict__ actions,
                    bf16* __restrict__ A, int m0)
{
    const int ml = blockIdx.x;
    const int m = m0 + ml;
    const int r = m / NA;
    const int a = m - r * NA;
    const int t = threadIdx.x;
    const float* src = (t < 128)
        ? hidden + (size_t)r * HH + t * 8
        : embed  + (size_t)actions[r*NA + a] * HH + (t - 128) * 8;
    float4 v0 = ((const float4*)src)[0];
    float4 v1 = ((const float4*)src)[1];
    bf16x8 o;
    o[0] = (bf16)v0.x; o[1] = (bf16)v0.y; o[2] = (bf16)v0.z; o[3] = (bf16)v0.w;
    o[4] = (bf16)v1.x; o[5] = (bf16)v1.y; o[6] = (bf16)v1.z; o[7] = (bf16)v1.w;
    *(bf16x8*)(A + (size_t)ml * INNER + t * 8) = o;
}

// ---------------------------------------------------------------------------
// Kernel 3: 128x128 MFMA GEMM (m97 structure: linear LDS + global_load_lds x16,
// 2-barrier K-loop, 4 waves each owning a 64x64 quadrant, 16x16x32 bf16 MFMA).
// C = A(Mx2048) * Bt(Nx2048)^T ; GELU epilogue -> bf16 out, or raw f32 out.
// ---------------------------------------------------------------------------
template<bool GELU>
__global__ __launch_bounds__(256, 2)
void gemm128_kernel(const bf16* __restrict__ A,
                    const bf16* __restrict__ Bt,
                    const float* __restrict__ bias,
                    bf16* __restrict__ outB,
                    float* __restrict__ outF,
                    int N)
{
    const int nb = blockIdx.x;
    const int mb = blockIdx.y;
    const int t = threadIdx.x;
    const int w = t >> 6, lane = t & 63;
    const int q = lane >> 4, c = lane & 15;
    const int wr = w >> 1, wc = w & 1;

    __shared__ __align__(16) bf16 sA[128 * 32];
    __shared__ __align__(16) bf16 sB[128 * 32];

    const int e0 = (w*2 + 0) * 512 + lane * 8;
    const int e1 = (w*2 + 1) * 512 + lane * 8;
    const bf16* gA0 = A  + (size_t)(mb*128 + (e0 >> 5)) * INNER + (e0 & 31);
    const bf16* gA1 = A  + (size_t)(mb*128 + (e1 >> 5)) * INNER + (e1 & 31);
    const bf16* gB0 = Bt + (size_t)(nb*128 + (e0 >> 5)) * INNER + (e0 & 31);
    const bf16* gB1 = Bt + (size_t)(nb*128 + (e1 >> 5)) * INNER + (e1 & 31);
    bf16* lA0 = sA + (w*2 + 0) * 512;
    bf16* lA1 = sA + (w*2 + 1) * 512;
    bf16* lB0 = sB + (w*2 + 0) * 512;
    bf16* lB1 = sB + (w*2 + 1) * 512;

    const f32x4 z4 = {0.f, 0.f, 0.f, 0.f};
    f32x4 acc[4][4];
#pragma unroll
    for (int mt = 0; mt < 4; ++mt)
#pragma unroll
        for (int nt = 0; nt < 4; ++nt) acc[mt][nt] = z4;

#pragma unroll 1
    for (int k0 = 0; k0 < INNER; k0 += 32) {
        gload16(gA0 + k0, lA0);
        gload16(gA1 + k0, lA1);
        gload16(gB0 + k0, lB0);
        gload16(gB1 + k0, lB1);
        __syncthreads();

        bf16x8 af[4], bfr[4];
#pragma unroll
        for (int mt = 0; mt < 4; ++mt)
            af[mt] = *(const bf16x8*)&sA[(wr*64 + mt*16 + c) * 32 + q*8];
#pragma unroll
        for (int nt = 0; nt < 4; ++nt)
            bfr[nt] = *(const bf16x8*)&sB[(wc*64 + nt*16 + c) * 32 + q*8];
#pragma unroll
        for (int mt = 0; mt < 4; ++mt)
#pragma unroll
            for (int nt = 0; nt < 4; ++nt)
                acc[mt][nt] = mfma16(af[mt], bfr[nt], acc[mt][nt]);
        __syncthreads();
    }

    const int mrow = mb*128 + wr*64;
    const int ncol = nb*128 + wc*64;
#pragma unroll
    for (int nt = 0; nt < 4; ++nt) {
        const int n = ncol + nt*16 + c;
        float bb = 0.f;
        if constexpr (GELU) bb = bias[n];
#pragma unroll
        for (int mt = 0; mt < 4; ++mt) {
#pragma unroll
            for (int reg = 0; reg < 4; ++reg) {
                const int m = mrow + mt*16 + q*4 + reg;
                if constexpr (GELU) {
                    const float x = acc[mt][nt][reg] + bb;
                    const float g = 0.5f * x * (1.f + erff(x * 0.70710678118654752f));
                    outB[(size_t)m * N + n] = (bf16)g;
                } else {
                    outF[(size_t)m * N + n] = acc[mt][nt][reg];
                }
            }
        }
    }
}

// ---------------------------------------------------------------------------
// Kernel 4: per action-row: +b2, LayerNorm, cosine(action_repr, future) -> score
// ---------------------------------------------------------------------------
__global__ __launch_bounds__(256)
void ln_cos_kernel(const float* __restrict__ D,
                   const float* __restrict__ b2,
                   const float* __restrict__ ln_g,
                   const float* __restrict__ ln_b,
                   const float* __restrict__ future,
                   int m0,
                   float* __restrict__ scores)
{
    const int ml = blockIdx.x;
    const int m = m0 + ml;
    const int r = m / NA;
    const int t = threadIdx.x;
    const int w = t >> 6, lane = t & 63;
    __shared__ float s1[4], s2[4], s3[4], s4[4], s5[4];

    float4 d  = ((const float4*)(D + (size_t)ml * HH))[t];
    float4 bb = ((const float4*)b2)[t];
    d.x += bb.x; d.y += bb.y; d.z += bb.z; d.w += bb.w;

    float p1 = d.x + d.y + d.z + d.w;
    float p2 = d.x*d.x + d.y*d.y + d.z*d.z + d.w*d.w;
#pragma unroll
    for (int m2 = 1; m2 < 64; m2 <<= 1) {
        p1 += __shfl_xor(p1, m2, 64);
        p2 += __shfl_xor(p2, m2, 64);
    }
    if (lane == 0) { s1[w] = p1; s2[w] = p2; }
    __syncthreads();
    const float S1 = s1[0] + s1[1] + s1[2] + s1[3];
    const float S2 = s2[0] + s2[1] + s2[2] + s2[3];
    const float mu = S1 * (1.f / (float)HH);
    const float rstd = rsqrtf(S2 * (1.f / (float)HH) - mu*mu + 1e-5f);

    float4 g = ((const float4*)ln_g)[t];
    float4 b = ((const float4*)ln_b)[t];
    float4 f = ((const float4*)(future + (size_t)r * HH))[t];
    float4 ar;
    ar.x = (d.x - mu) * rstd * g.x + b.x;
    ar.y = (d.y - mu) * rstd * g.y + b.y;
    ar.z = (d.z - mu) * rstd * g.z + b.z;
    ar.w = (d.w - mu) * rstd * g.w + b.w;
    float paa = ar.x*ar.x + ar.y*ar.y + ar.z*ar.z + ar.w*ar.w;
    float paf = ar.x*f.x  + ar.y*f.y  + ar.z*f.z  + ar.w*f.w;
    float pff = f.x*f.x   + f.y*f.y   + f.z*f.z   + f.w*f.w;
#pragma unroll
    for (int m2 = 1; m2 < 64; m2 <<= 1) {
        paa += __shfl_xor(paa, m2, 64);
        paf += __shfl_xor(paf, m2, 64);
        pff += __shfl_xor(pff, m2, 64);
    }
    if (lane == 0) { s3[w] = paa; s4[w] = paf; s5[w] = pff; }
    __syncthreads();
    if (t == 0) {
        const float Saa = s3[0] + s3[1] + s3[2] + s3[3];
        const float Saf = s4[0] + s4[1] + s4[2] + s4[3];
        const float Sff = s5[0] + s5[1] + s5[2] + s5[3];
        const float anorm = fmaxf(sqrtf(Saa), 1e-12f);
        const float fnorm = fmaxf(sqrtf(Sff), 1e-12f);
        scores[m] = Saf / (anorm * fnorm);
    }
}

// ---------------------------------------------------------------------------
// Kernel 5: per token-row softmax over 17 scores + loss accumulation
// ---------------------------------------------------------------------------
__global__ __launch_bounds__(256)
void loss_kernel(const float* __restrict__ scores,
                 const int* __restrict__ amask,
                 const float* __restrict__ lp,
                 const int* __restrict__ rvalid,
                 const int* __restrict__ validcount,
                 float* __restrict__ out)
{
    const int r = blockIdx.x * blockDim.x + threadIdx.x;
    if (r >= BTOT) return;
    float sc[NA];
    float mx = -INFINITY;
#pragma unroll
    for (int a = 0; a < NA; ++a) {
        sc[a] = amask[r*NA + a] ? scores[r*NA + a] : -1e9f;
        mx = fmaxf(mx, sc[a]);
    }
    float ex[NA]; float ses = 0.f;
#pragma unroll
    for (int a = 0; a < NA; ++a) { ex[a] = __expf(sc[a] - mx); ses += ex[a]; }
    const int validr = rvalid[r];
    float acc = 0.f; int denom = 0;
#pragma unroll
    for (int a = 0; a < NA; ++a) {
        const int mk = amask[r*NA + a];
        const int mv = (mk && validr) ? 1 : 0;
        const float rw = (ex[a] / ses) * (float)mk;
        acc += rw * lp[r*NA + a] * (float)mv;
        denom += mv;
    }
    const float lossr = -acc / (float)(denom > 0 ? denom : 1) * (float)validr;
    atomicAdd(out, lossr / fmaxf((float)(*validcount), 1.f));
}

// ---------------------------------------------------------------------------
extern "C" void kernel_launch(void* const* d_in, const int* in_sizes, int n_in,
                              void* d_out, int out_size, void* d_ws, size_t ws_size,
                              hipStream_t stream)
{
    const float* logits        = (const float*)d_in[0];
    const float* hidden        = (const float*)d_in[1];
    const int*   labels        = (const int*)d_in[2];
    const float* future        = (const float*)d_in[3];
    const unsigned char* fvld  = (const unsigned char*)d_in[4];
    const float* embed         = (const float*)d_in[5];
    const float* W1f           = (const float*)d_in[6];
    const float* b1            = (const float*)d_in[7];
    const float* W2f           = (const float*)d_in[8];
    const float* b2            = (const float*)d_in[9];
    const float* ln_g          = (const float*)d_in[10];
    const float* ln_b          = (const float*)d_in[11];
    float* out = (float*)d_out;

    char* ws = (char*)d_ws;
    size_t off = 0;
    bf16* W1T = (bf16*)(ws + off); off += (size_t)INNER * INNER * 2;   // 8 MB
    bf16* W2T = (bf16*)(ws + off); off += (size_t)HH * INNER * 2;      // 4 MB
    int*   validcount = (int*)(ws + off);   off += 256;
    int*   actions    = (int*)(ws + off);   off += (size_t)MTOT * 4;
    int*   amask      = (int*)(ws + off);   off += (size_t)MTOT * 4;
    float* lp         = (float*)(ws + off); off += (size_t)MTOT * 4;
    int*   rvalid     = (int*)(ws + off);   off += (size_t)BTOT * 4;
    float* scores     = (float*)(ws + off); off += (size_t)MTOT * 4;
    off = (off + 255) & ~(size_t)255;

    // adaptive slab, strictly within ws_size:
    // per 128-row block: A bf16 (aliased later by D f32) 512KB + Y bf16 512KB
    size_t rem = (ws_size > off) ? (ws_size - off) : 0;
    long long cap_blocks = (long long)(rem / ((size_t)8192 * 128));
    int slab_blocks = (cap_blocks > (MTOT/128)) ? (MTOT/128) : (int)cap_blocks;
    if (slab_blocks < 1) slab_blocks = 1;
    const int slab_rows_max = slab_blocks * 128;

    bf16*  Abuf = (bf16*)(ws + off);
    float* Dbuf = (float*)Abuf;   // D aliases A (A dead after GEMM1 of same slab)
    bf16*  Ybuf = (bf16*)(ws + off + (size_t)slab_rows_max * 4096);

    (void)hipMemsetAsync(d_out, 0, sizeof(float), stream);
    (void)hipMemsetAsync(validcount, 0, 16, stream);

    transpose_to_bf16<<<dim3(INNER/32, INNER/32), dim3(32, 8), 0, stream>>>(W1f, W1T, INNER, INNER);
    transpose_to_bf16<<<dim3(HH/32,    INNER/32), dim3(32, 8), 0, stream>>>(W2f, W2T, INNER, HH);

    topk_lse_kernel<<<BTOT, 256, 0, stream>>>(logits, labels, fvld,
                                              actions, amask, lp, rvalid, validcount);

    for (int m0 = 0; m0 < MTOT; m0 += slab_rows_max) {
        const int rows = (MTOT - m0 < slab_rows_max) ? (MTOT - m0) : slab_rows_max;
        const int nbm = rows / 128;
        build_a_kernel<<<rows, 256, 0, stream>>>(hidden, embed, actions, Abuf, m0);
        gemm128_kernel<true ><<<dim3(INNER/128, nbm), 256, 0, stream>>>(
            Abuf, W1T, b1, Ybuf, nullptr, INNER);
        gemm128_kernel<false><<<dim3(HH/128, nbm), 256, 0, stream>>>(
            Ybuf, W2T, nullptr, nullptr, Dbuf, HH);
        ln_cos_kernel<<<rows, 256, 0, stream>>>(Dbuf, b2, ln_g, ln_b, future, m0, scores);
    }

    loss_kernel<<<(BTOT + 255) / 256, 256, 0, stream>>>(scores, amask, lp,
                                                        rvalid, validcount, out);
}

// Round 5
// 1110.592 us; speedup vs baseline: 7.5302x; 1.0838x over previous
//
#include <hip/hip_runtime.h>
#include <hip/hip_bf16.h>
#include <math.h>

#define BTOT 2048
#define VV 32000
#define HH 1024
#define INNER 2048
#define NA 17
#define MTOT (BTOT * NA)   // 34816 action-rows = 272 * 128
#define CAP 1088           // candidate buffer (provable worst case <= 1024)

typedef __bf16 bf16;
typedef __bf16 bf16x8 __attribute__((ext_vector_type(8)));
typedef float f32x4 __attribute__((ext_vector_type(4)));

__device__ __forceinline__ f32x4 mfma16(bf16x8 a, bf16x8 b, f32x4 c) {
    return __builtin_amdgcn_mfma_f32_16x16x32_bf16(a, b, c, 0, 0, 0);
}

// async global->LDS, 16B per lane; LDS dest is wave-uniform base + lane*16
__device__ __forceinline__ void gload16(const void* g, void* l) {
    __builtin_amdgcn_global_load_lds(
        (const __attribute__((address_space(1))) unsigned int*)g,
        (__attribute__((address_space(3))) unsigned int*)l, 16, 0, 0);
}

__device__ __forceinline__ bool vi_better(float va, int ia, float vb, int ib) {
    // jax.lax.top_k order: larger value first; ties -> smaller index first
    return (va > vb) || (va == vb && ia < ib);
}

// ---------------------------------------------------------------------------
// Kernel 0: tiled transpose f32 -> bf16.  dst[c][r] = (bf16)src[r][c]
// ---------------------------------------------------------------------------
__global__ __launch_bounds__(256)
void transpose_to_bf16(const float* __restrict__ src, bf16* __restrict__ dst,
                       int R, int C)
{
    __shared__ float tile[32][33];
    const int bx = blockIdx.x * 32;
    const int by = blockIdx.y * 32;
    const int tx = threadIdx.x;
    const int ty = threadIdx.y;
#pragma unroll
    for (int i = 0; i < 32; i += 8)
        tile[ty + i][tx] = src[(size_t)(by + ty + i) * C + bx + tx];
    __syncthreads();
#pragma unroll
    for (int i = 0; i < 32; i += 8)
        dst[(size_t)(bx + ty + i) * R + by + tx] = (bf16)tile[tx][ty + i];
}

// ---------------------------------------------------------------------------
// Kernel 0b: cast hidden f32 -> bf16 (2048 x 1024)
// ---------------------------------------------------------------------------
__global__ __launch_bounds__(256)
void cast_hidden_kernel(const float* __restrict__ hidden, bf16* __restrict__ hb)
{
    const size_t i = ((size_t)blockIdx.x * 256 + threadIdx.x) * 8;
    float4 v0 = ((const float4*)(hidden + i))[0];
    float4 v1 = ((const float4*)(hidden + i))[1];
    bf16x8 o;
    o[0] = (bf16)v0.x; o[1] = (bf16)v0.y; o[2] = (bf16)v0.z; o[3] = (bf16)v0.w;
    o[4] = (bf16)v1.x; o[5] = (bf16)v1.y; o[6] = (bf16)v1.z; o[7] = (bf16)v1.w;
    *(bf16x8*)(hb + i) = o;
}

// ---------------------------------------------------------------------------
// Kernel 1: per-row top-16 + LSE, two-pass threshold select
// ---------------------------------------------------------------------------
__global__ __launch_bounds__(256)
void topk_lse_kernel(const float* __restrict__ logits,
                     const int* __restrict__ labels,
                     const unsigned char* __restrict__ future_valid,
                     int* __restrict__ actions,
                     int* __restrict__ amask,
                     float* __restrict__ lp,
                     int* __restrict__ rvalid,
                     int* __restrict__ validcount)
{
    const int r = blockIdx.x;
    const int t = threadIdx.x;
    const float* __restrict__ lrow = logits + (size_t)r * VV;

    __shared__ float s_cv[CAP];
    __shared__ int   s_ci[CAP];
    __shared__ float candv[256];
    __shared__ int   candi[256];
    __shared__ float s_topv[16];
    __shared__ int   s_topi[16];
    __shared__ int   s_wtid;
    __shared__ int   s_cnt;
    __shared__ float s_redv[256];
    __shared__ int   s_redi[256];
    __shared__ int   s_redp[256];

    // ---- pass 1: per-thread top-2 (branchless) ----
    float m1 = -INFINITY, m2 = -INFINITY;
    int   i1 = 0x7fffffff, i2 = 0x7fffffff;
    const float4* __restrict__ lrow4 = (const float4*)lrow;
    for (int i = 0; i < 32; ++i) {
        int i4 = t + 256 * i;
        if (i4 < VV / 4) {
            float4 xv = lrow4[i4];
            float xs[4] = {xv.x, xv.y, xv.z, xv.w};
#pragma unroll
            for (int cc = 0; cc < 4; ++cc) {
                float x = xs[cc];
                int idx = i4 * 4 + cc;
                bool b1 = x > m1;
                bool b2 = x > m2;
                float nm2 = b1 ? m1 : (b2 ? x : m2);
                int   ni2 = b1 ? i1 : (b2 ? idx : i2);
                m1 = b1 ? x : m1;
                i1 = b1 ? idx : i1;
                m2 = nm2; i2 = ni2;
            }
        }
    }
    candv[t] = m1; candi[t] = i1;
    if (t == 0) s_cnt = 0;
    __syncthreads();

    // ---- extraction over 512 candidates: 16 rounds -> T = 16th (lex) ----
    int cur = 0;
    for (int round = 0; round < 16; ++round) {
        if (t < 64) {
            float bv = -INFINITY; int bi = 0x7fffffff; int btid = -1;
#pragma unroll
            for (int k2 = 0; k2 < 4; ++k2) {
                int tid = t + 64 * k2;
                float v = candv[tid]; int ii = candi[tid];
                if (vi_better(v, ii, bv, bi)) { bv = v; bi = ii; btid = tid; }
            }
#pragma unroll
            for (int ms = 1; ms < 64; ms <<= 1) {
                float ov = __shfl_xor(bv, ms, 64);
                int   oi = __shfl_xor(bi, ms, 64);
                int   ot = __shfl_xor(btid, ms, 64);
                if (vi_better(ov, oi, bv, bi)) { bv = ov; bi = oi; btid = ot; }
            }
            if (t == 0) { s_topv[round] = bv; s_topi[round] = bi; s_wtid = btid; }
        }
        __syncthreads();
        if (t == s_wtid) {
            ++cur;
            candv[t] = (cur < 2) ? m2 : -INFINITY;
            candi[t] = (cur < 2) ? i2 : 0x7fffffff;
        }
        __syncthreads();
    }

    const float M  = s_topv[0];
    const float Tv = s_topv[15];
    const int   Ti = s_topi[15];

    // ---- pass 2: LSE sum (branchless) + candidate collection ----
    float lsum = 0.f;
    for (int i = 0; i < 32; ++i) {
        int i4 = t + 256 * i;
        if (i4 < VV / 4) {
            float4 xv = lrow4[i4];
            float xs[4] = {xv.x, xv.y, xv.z, xv.w};
#pragma unroll
            for (int cc = 0; cc < 4; ++cc) {
                float x = xs[cc];
                int idx = i4 * 4 + cc;
                lsum += __expf(x - M);
                if (!vi_better(Tv, Ti, x, idx)) {   // (x,idx) >= (Tv,Ti) lex
                    int p = atomicAdd(&s_cnt, 1);
                    if (p < CAP) { s_cv[p] = x; s_ci[p] = idx; }
                }
            }
        }
    }
    s_redv[t] = lsum;
    __syncthreads();
    for (int s = 128; s > 0; s >>= 1) {
        if (t < s) s_redv[t] += s_redv[t + s];
        __syncthreads();
    }
    const float lse = M + logf(s_redv[0]);
    int C = s_cnt; if (C > CAP) C = CAP;
    __syncthreads();

    // ---- final exact top-16 over collected candidates ----
    for (int round = 0; round < 16; ++round) {
        float bv = -INFINITY; int bi = 0x7fffffff; int bp = -1;
        for (int j = t; j < C; j += 256) {
            float v = s_cv[j]; int ii = s_ci[j];
            if (vi_better(v, ii, bv, bi)) { bv = v; bi = ii; bp = j; }
        }
        s_redv[t] = bv; s_redi[t] = bi; s_redp[t] = bp;
        __syncthreads();
        if (t < 64) {
#pragma unroll
            for (int k2 = 1; k2 < 4; ++k2) {
                float v = s_redv[t + 64*k2]; int ii = s_redi[t + 64*k2];
                int pp = s_redp[t + 64*k2];
                if (vi_better(v, ii, bv, bi)) { bv = v; bi = ii; bp = pp; }
            }
#pragma unroll
            for (int ms = 1; ms < 64; ms <<= 1) {
                float ov = __shfl_xor(bv, ms, 64);
                int   oi = __shfl_xor(bi, ms, 64);
                int   op = __shfl_xor(bp, ms, 64);
                if (vi_better(ov, oi, bv, bi)) { bv = ov; bi = oi; bp = op; }
            }
            if (t == 0) {
                s_topv[round] = bv; s_topi[round] = bi;
                if (bp >= 0) { s_cv[bp] = -INFINITY; s_ci[bp] = 0x7fffffff; }
            }
        }
        __syncthreads();
    }

    // ---- epilogue ----
    int lbl = labels[r];
    if (t < 16) {
        actions[r*NA + t] = s_topi[t];
        amask[r*NA + t]   = 1;
        lp[r*NA + t]      = s_topv[t] - lse;
    } else if (t == 16) {
        bool dup = false;
#pragma unroll
        for (int k = 0; k < 16; ++k) dup = dup || (s_topi[k] == lbl);
        actions[r*NA + 16] = dup ? 0 : lbl;
        amask[r*NA + 16]   = dup ? 0 : 1;
        lp[r*NA + 16]      = dup ? 0.f : (lrow[lbl] - lse);
        bool valid = (lbl != -100) && (future_valid[r] != 0);
        rvalid[r] = valid ? 1 : 0;
        if (valid) atomicAdd(validcount, 1);
    }
}

// ---------------------------------------------------------------------------
// Kernel 2: gather embed rows -> bf16 AE (2 rows per 256-thread block)
// ---------------------------------------------------------------------------
__global__ __launch_bounds__(256)
void build_embed_kernel(const float* __restrict__ embed,
                        const int* __restrict__ actions,
                        bf16* __restrict__ AE, int m0)
{
    const int t = threadIdx.x;
    const int ml = blockIdx.x * 2 + (t >> 7);
    const int gm = m0 + ml;
    const int r = gm / NA;
    const int a = gm - r * NA;
    const int tt = t & 127;
    const float* src = embed + (size_t)actions[r*NA + a] * HH + tt * 8;
    float4 v0 = ((const float4*)src)[0];
    float4 v1 = ((const float4*)src)[1];
    bf16x8 o;
    o[0] = (bf16)v0.x; o[1] = (bf16)v0.y; o[2] = (bf16)v0.z; o[3] = (bf16)v0.w;
    o[4] = (bf16)v1.x; o[5] = (bf16)v1.y; o[6] = (bf16)v1.z; o[7] = (bf16)v1.w;
    *(bf16x8*)(AE + (size_t)ml * HH + tt * 8) = o;
}

// ---------------------------------------------------------------------------
// Kernel 3: 128x128 MFMA GEMM (m97 structure), XCD-chunked block swizzle.
// C = A(MxK, stride lda) * Bt(NxK, stride ldb, col offset koff)^T
// MODE 0: outF = acc                (GEMM2 -> D f32)
// MODE 1: outB = GELU(acc + Hpre[(m0+m)/NA][n])   (GEMM1' -> Y bf16)
// MODE 2: outF = acc + bias[n]      (Hpre = hidden @ W1_top + b1)
// grid is 1D, nwg % 8 == 0 (always true: grids are 256, 16*nbm, 8*nbm).
// ---------------------------------------------------------------------------
template<int MODE>
__global__ __launch_bounds__(256, 2)
void gemm128(const bf16* __restrict__ A, int lda,
             const bf16* __restrict__ Bt, int ldb, int koff, int K,
             const float* __restrict__ extra,
             bf16* __restrict__ outB, float* __restrict__ outF,
             int ldo, int nbx, int m0)
{
    const int nwg = gridDim.x;
    const int per = nwg >> 3;
    const int id  = blockIdx.x;
    const int sid = (id & 7) * per + (id >> 3);   // XCD-chunked (bijective)
    const int nb = sid % nbx;
    const int mb = sid / nbx;

    const int t = threadIdx.x;
    const int w = t >> 6, lane = t & 63;
    const int q = lane >> 4, c = lane & 15;
    const int wr = w >> 1, wc = w & 1;

    __shared__ __align__(16) bf16 sA[128 * 32];
    __shared__ __align__(16) bf16 sB[128 * 32];

    const int e0 = (w*2 + 0) * 512 + lane * 8;
    const int e1 = (w*2 + 1) * 512 + lane * 8;
    const bf16* gA0 = A  + (size_t)(mb*128 + (e0 >> 5)) * lda + (e0 & 31);
    const bf16* gA1 = A  + (size_t)(mb*128 + (e1 >> 5)) * lda + (e1 & 31);
    const bf16* gB0 = Bt + (size_t)(nb*128 + (e0 >> 5)) * ldb + koff + (e0 & 31);
    const bf16* gB1 = Bt + (size_t)(nb*128 + (e1 >> 5)) * ldb + koff + (e1 & 31);
    bf16* lA0 = sA + (w*2 + 0) * 512;
    bf16* lA1 = sA + (w*2 + 1) * 512;
    bf16* lB0 = sB + (w*2 + 0) * 512;
    bf16* lB1 = sB + (w*2 + 1) * 512;

    const f32x4 z4 = {0.f, 0.f, 0.f, 0.f};
    f32x4 acc[4][4];
#pragma unroll
    for (int mt = 0; mt < 4; ++mt)
#pragma unroll
        for (int nt = 0; nt < 4; ++nt) acc[mt][nt] = z4;

#pragma unroll 1
    for (int k0 = 0; k0 < K; k0 += 32) {
        gload16(gA0 + k0, lA0);
        gload16(gA1 + k0, lA1);
        gload16(gB0 + k0, lB0);
        gload16(gB1 + k0, lB1);
        __syncthreads();

        bf16x8 af[4], bfr[4];
#pragma unroll
        for (int mt = 0; mt < 4; ++mt)
            af[mt] = *(const bf16x8*)&sA[(wr*64 + mt*16 + c) * 32 + q*8];
#pragma unroll
        for (int nt = 0; nt < 4; ++nt)
            bfr[nt] = *(const bf16x8*)&sB[(wc*64 + nt*16 + c) * 32 + q*8];
#pragma unroll
        for (int mt = 0; mt < 4; ++mt)
#pragma unroll
            for (int nt = 0; nt < 4; ++nt)
                acc[mt][nt] = mfma16(af[mt], bfr[nt], acc[mt][nt]);
        __syncthreads();
    }

    const int mrow = mb*128 + wr*64;
    const int ncol = nb*128 + wc*64;
#pragma unroll
    for (int nt = 0; nt < 4; ++nt) {
        const int n = ncol + nt*16 + c;
        float bb = 0.f;
        if constexpr (MODE == 2) bb = extra[n];
#pragma unroll
        for (int mt = 0; mt < 4; ++mt) {
#pragma unroll
            for (int reg = 0; reg < 4; ++reg) {
                const int m = mrow + mt*16 + q*4 + reg;
                float x = acc[mt][nt][reg];
                if constexpr (MODE == 0) {
                    outF[(size_t)m * ldo + n] = x;
                } else if constexpr (MODE == 1) {
                    const int gr = (m0 + m) / NA;
                    x += extra[(size_t)gr * INNER + n];
                    const float g = 0.5f * x * (1.f + erff(x * 0.70710678118654752f));
                    outB[(size_t)m * ldo + n] = (bf16)g;
                } else {
                    outF[(size_t)m * ldo + n] = x + bb;
                }
            }
        }
    }
}

// ---------------------------------------------------------------------------
// Kernel 4: per action-row: +b2, LayerNorm, cosine(action_repr, future) -> score
// ---------------------------------------------------------------------------
__global__ __launch_bounds__(256)
void ln_cos_kernel(const float* __restrict__ D,
                   const float* __restrict__ b2,
                   const float* __restrict__ ln_g,
                   const float* __restrict__ ln_b,
                   const float* __restrict__ future,
                   int m0,
                   float* __restrict__ scores)
{
    const int ml = blockIdx.x;
    const int m = m0 + ml;
    const int r = m / NA;
    const int t = threadIdx.x;
    const int w = t >> 6, lane = t & 63;
    __shared__ float s1[4], s2[4], s3[4], s4[4], s5[4];

    float4 d  = ((const float4*)(D + (size_t)ml * HH))[t];
    float4 bb = ((const float4*)b2)[t];
    d.x += bb.x; d.y += bb.y; d.z += bb.z; d.w += bb.w;

    float p1 = d.x + d.y + d.z + d.w;
    float p2 = d.x*d.x + d.y*d.y + d.z*d.z + d.w*d.w;
#pragma unroll
    for (int m2 = 1; m2 < 64; m2 <<= 1) {
        p1 += __shfl_xor(p1, m2, 64);
        p2 += __shfl_xor(p2, m2, 64);
    }
    if (lane == 0) { s1[w] = p1; s2[w] = p2; }
    __syncthreads();
    const float S1 = s1[0] + s1[1] + s1[2] + s1[3];
    const float S2 = s2[0] + s2[1] + s2[2] + s2[3];
    const float mu = S1 * (1.f / (float)HH);
    const float rstd = rsqrtf(S2 * (1.f / (float)HH) - mu*mu + 1e-5f);

    float4 g = ((const float4*)ln_g)[t];
    float4 b = ((const float4*)ln_b)[t];
    float4 f = ((const float4*)(future + (size_t)r * HH))[t];
    float4 ar;
    ar.x = (d.x - mu) * rstd * g.x + b.x;
    ar.y = (d.y - mu) * rstd * g.y + b.y;
    ar.z = (d.z - mu) * rstd * g.z + b.z;
    ar.w = (d.w - mu) * rstd * g.w + b.w;
    float paa = ar.x*ar.x + ar.y*ar.y + ar.z*ar.z + ar.w*ar.w;
    float paf = ar.x*f.x  + ar.y*f.y  + ar.z*f.z  + ar.w*f.w;
    float pff = f.x*f.x   + f.y*f.y   + f.z*f.z   + f.w*f.w;
#pragma unroll
    for (int m2 = 1; m2 < 64; m2 <<= 1) {
        paa += __shfl_xor(paa, m2, 64);
        paf += __shfl_xor(paf, m2, 64);
        pff += __shfl_xor(pff, m2, 64);
    }
    if (lane == 0) { s3[w] = paa; s4[w] = paf; s5[w] = pff; }
    __syncthreads();
    if (t == 0) {
        const float Saa = s3[0] + s3[1] + s3[2] + s3[3];
        const float Saf = s4[0] + s4[1] + s4[2] + s4[3];
        const float Sff = s5[0] + s5[1] + s5[2] + s5[3];
        const float anorm = fmaxf(sqrtf(Saa), 1e-12f);
        const float fnorm = fmaxf(sqrtf(Sff), 1e-12f);
        scores[m] = Saf / (anorm * fnorm);
    }
}

// ---------------------------------------------------------------------------
// Kernel 5: per token-row softmax over 17 scores + loss accumulation
// ---------------------------------------------------------------------------
__global__ __launch_bounds__(256)
void loss_kernel(const float* __restrict__ scores,
                 const int* __restrict__ amask,
                 const float* __restrict__ lp,
                 const int* __restrict__ rvalid,
                 const int* __restrict__ validcount,
                 float* __restrict__ out)
{
    const int r = blockIdx.x * blockDim.x + threadIdx.x;
    if (r >= BTOT) return;
    float sc[NA];
    float mx = -INFINITY;
#pragma unroll
    for (int a = 0; a < NA; ++a) {
        sc[a] = amask[r*NA + a] ? scores[r*NA + a] : -1e9f;
        mx = fmaxf(mx, sc[a]);
    }
    float ex[NA]; float ses = 0.f;
#pragma unroll
    for (int a = 0; a < NA; ++a) { ex[a] = __expf(sc[a] - mx); ses += ex[a]; }
    const int validr = rvalid[r];
    float acc = 0.f; int denom = 0;
#pragma unroll
    for (int a = 0; a < NA; ++a) {
        const int mk = amask[r*NA + a];
        const int mv = (mk && validr) ? 1 : 0;
        const float rw = (ex[a] / ses) * (float)mk;
        acc += rw * lp[r*NA + a] * (float)mv;
        denom += mv;
    }
    const float lossr = -acc / (float)(denom > 0 ? denom : 1) * (float)validr;
    atomicAdd(out, lossr / fmaxf((float)(*validcount), 1.f));
}

// ---------------------------------------------------------------------------
extern "C" void kernel_launch(void* const* d_in, const int* in_sizes, int n_in,
                              void* d_out, int out_size, void* d_ws, size_t ws_size,
                              hipStream_t stream)
{
    const float* logits        = (const float*)d_in[0];
    const float* hidden        = (const float*)d_in[1];
    const int*   labels        = (const int*)d_in[2];
    const float* future        = (const float*)d_in[3];
    const unsigned char* fvld  = (const unsigned char*)d_in[4];
    const float* embed         = (const float*)d_in[5];
    const float* W1f           = (const float*)d_in[6];
    const float* b1            = (const float*)d_in[7];
    const float* W2f           = (const float*)d_in[8];
    const float* b2            = (const float*)d_in[9];
    const float* ln_g          = (const float*)d_in[10];
    const float* ln_b          = (const float*)d_in[11];
    float* out = (float*)d_out;

    // ws layout: W1T | W2T | hiddenB | Hpre | counters | per-row arrays | slab
    char* ws = (char*)d_ws;
    size_t off = 0;
    bf16*  W1T   = (bf16*)(ws + off);  off += (size_t)INNER * INNER * 2;  // 8 MB
    bf16*  W2T   = (bf16*)(ws + off);  off += (size_t)HH * INNER * 2;     // 4 MB
    bf16*  hidB  = (bf16*)(ws + off);  off += (size_t)BTOT * HH * 2;      // 4 MB
    float* Hpre  = (float*)(ws + off); off += (size_t)BTOT * INNER * 4;   // 16 MB
    int*   validcount = (int*)(ws + off);   off += 256;
    int*   actions    = (int*)(ws + off);   off += (size_t)MTOT * 4;
    int*   amask      = (int*)(ws + off);   off += (size_t)MTOT * 4;
    float* lp         = (float*)(ws + off); off += (size_t)MTOT * 4;
    int*   rvalid     = (int*)(ws + off);   off += (size_t)BTOT * 4;
    float* scores     = (float*)(ws + off); off += (size_t)MTOT * 4;
    off = (off + 255) & ~(size_t)255;

    // slab per 128-row block: AE bf16 (256KB) + Y bf16 (512KB) + D f32 (512KB)
    size_t rem = (ws_size > off) ? (ws_size - off) : 0;
    long long cap_blocks = (long long)(rem / ((size_t)10240 * 128));
    int slab_blocks = (cap_blocks > (MTOT/128)) ? (MTOT/128) : (int)cap_blocks;
    if (slab_blocks < 1) slab_blocks = 1;
    const int slab_rows_max = slab_blocks * 128;

    bf16*  AEbuf = (bf16*)(ws + off);
    bf16*  Ybuf  = (bf16*)(ws + off + (size_t)slab_rows_max * 2048);
    float* Dbuf  = (float*)(ws + off + (size_t)slab_rows_max * (2048 + 4096));

    (void)hipMemsetAsync(d_out, 0, sizeof(float), stream);
    (void)hipMemsetAsync(validcount, 0, 16, stream);

    transpose_to_bf16<<<dim3(INNER/32, INNER/32), dim3(32, 8), 0, stream>>>(W1f, W1T, INNER, INNER);
    transpose_to_bf16<<<dim3(HH/32,    INNER/32), dim3(32, 8), 0, stream>>>(W2f, W2T, INNER, HH);
    cast_hidden_kernel<<<(BTOT*HH)/2048, 256, 0, stream>>>(hidden, hidB);

    // Hpre = hidden @ W1_top + b1   (M=2048, N=2048, K=1024)
    gemm128<2><<<(INNER/128) * (BTOT/128), 256, 0, stream>>>(
        hidB, HH, W1T, INNER, 0, HH, b1, nullptr, Hpre, INNER, INNER/128, 0);

    topk_lse_kernel<<<BTOT, 256, 0, stream>>>(logits, labels, fvld,
                                              actions, amask, lp, rvalid, validcount);

    for (int m0 = 0; m0 < MTOT; m0 += slab_rows_max) {
        const int rows = (MTOT - m0 < slab_rows_max) ? (MTOT - m0) : slab_rows_max;
        const int nbm = rows / 128;
        build_embed_kernel<<<rows/2, 256, 0, stream>>>(embed, actions, AEbuf, m0);
        // Y = GELU(AE @ W1_bot + Hpre[row])   (N=2048, K=1024, koff=1024)
        gemm128<1><<<(INNER/128) * nbm, 256, 0, stream>>>(
            AEbuf, HH, W1T, INNER, HH, HH, Hpre, Ybuf, nullptr, INNER, INNER/128, m0);
        // D = Y @ W2T                          (N=1024, K=2048)
        gemm128<0><<<(HH/128) * nbm, 256, 0, stream>>>(
            Ybuf, INNER, W2T, INNER, 0, INNER, nullptr, nullptr, Dbuf, HH, HH/128, 0);
        ln_cos_kernel<<<rows, 256, 0, stream>>>(Dbuf, b2, ln_g, ln_b, future, m0, scores);
    }

    loss_kernel<<<(BTOT + 255) / 256, 256, 0, stream>>>(scores, amask, lp,
                                                        rvalid, validcount, out);
}

// Round 6
// 1090.842 us; speedup vs baseline: 7.6666x; 1.0181x over previous
//
#include <hip/hip_runtime.h>
#include <hip/hip_bf16.h>
#include <math.h>

#define BTOT 2048
#define VV 32000
#define HH 1024
#define INNER 2048
#define NA 17
#define MTOT (BTOT * NA)   // 34816 action-rows = 272 * 128
#define CAP 1088           // candidate buffer (provable worst case <= 1024)

typedef __bf16 bf16;
typedef __bf16 bf16x8 __attribute__((ext_vector_type(8)));
typedef float f32x4 __attribute__((ext_vector_type(4)));

__device__ __forceinline__ f32x4 mfma16(bf16x8 a, bf16x8 b, f32x4 c) {
    return __builtin_amdgcn_mfma_f32_16x16x32_bf16(a, b, c, 0, 0, 0);
}

// async global->LDS, 16B per lane; LDS dest is wave-uniform base + lane*16
__device__ __forceinline__ void gload16(const void* g, void* l) {
    __builtin_amdgcn_global_load_lds(
        (const __attribute__((address_space(1))) unsigned int*)g,
        (__attribute__((address_space(3))) unsigned int*)l, 16, 0, 0);
}

__device__ __forceinline__ bool vi_better(float va, int ia, float vb, int ib) {
    // jax.lax.top_k order: larger value first; ties -> smaller index first
    return (va > vb) || (va == vb && ia < ib);
}

// ---------------------------------------------------------------------------
// Kernel 0: tiled transpose f32 -> bf16.  dst[c][r] = (bf16)src[r][c]
// ---------------------------------------------------------------------------
__global__ __launch_bounds__(256)
void transpose_to_bf16(const float* __restrict__ src, bf16* __restrict__ dst,
                       int R, int C)
{
    __shared__ float tile[32][33];
    const int bx = blockIdx.x * 32;
    const int by = blockIdx.y * 32;
    const int tx = threadIdx.x;
    const int ty = threadIdx.y;
#pragma unroll
    for (int i = 0; i < 32; i += 8)
        tile[ty + i][tx] = src[(size_t)(by + ty + i) * C + bx + tx];
    __syncthreads();
#pragma unroll
    for (int i = 0; i < 32; i += 8)
        dst[(size_t)(bx + ty + i) * R + by + tx] = (bf16)tile[tx][ty + i];
}

// ---------------------------------------------------------------------------
// Kernel 0b: cast hidden f32 -> bf16 (2048 x 1024)
// ---------------------------------------------------------------------------
__global__ __launch_bounds__(256)
void cast_hidden_kernel(const float* __restrict__ hidden, bf16* __restrict__ hb)
{
    const size_t i = ((size_t)blockIdx.x * 256 + threadIdx.x) * 8;
    float4 v0 = ((const float4*)(hidden + i))[0];
    float4 v1 = ((const float4*)(hidden + i))[1];
    bf16x8 o;
    o[0] = (bf16)v0.x; o[1] = (bf16)v0.y; o[2] = (bf16)v0.z; o[3] = (bf16)v0.w;
    o[4] = (bf16)v1.x; o[5] = (bf16)v1.y; o[6] = (bf16)v1.z; o[7] = (bf16)v1.w;
    *(bf16x8*)(hb + i) = o;
}

// ---------------------------------------------------------------------------
// Kernel 1: per-row top-16 + LSE, two-pass threshold select (unchanged)
// ---------------------------------------------------------------------------
__global__ __launch_bounds__(256)
void topk_lse_kernel(const float* __restrict__ logits,
                     const int* __restrict__ labels,
                     const unsigned char* __restrict__ future_valid,
                     int* __restrict__ actions,
                     int* __restrict__ amask,
                     float* __restrict__ lp,
                     int* __restrict__ rvalid,
                     int* __restrict__ validcount)
{
    const int r = blockIdx.x;
    const int t = threadIdx.x;
    const float* __restrict__ lrow = logits + (size_t)r * VV;

    __shared__ float s_cv[CAP];
    __shared__ int   s_ci[CAP];
    __shared__ float candv[256];
    __shared__ int   candi[256];
    __shared__ float s_topv[16];
    __shared__ int   s_topi[16];
    __shared__ int   s_wtid;
    __shared__ int   s_cnt;
    __shared__ float s_redv[256];
    __shared__ int   s_redi[256];
    __shared__ int   s_redp[256];

    // ---- pass 1: per-thread top-2 (branchless) ----
    float m1 = -INFINITY, m2 = -INFINITY;
    int   i1 = 0x7fffffff, i2 = 0x7fffffff;
    const float4* __restrict__ lrow4 = (const float4*)lrow;
    for (int i = 0; i < 32; ++i) {
        int i4 = t + 256 * i;
        if (i4 < VV / 4) {
            float4 xv = lrow4[i4];
            float xs[4] = {xv.x, xv.y, xv.z, xv.w};
#pragma unroll
            for (int cc = 0; cc < 4; ++cc) {
                float x = xs[cc];
                int idx = i4 * 4 + cc;
                bool b1 = x > m1;
                bool b2 = x > m2;
                float nm2 = b1 ? m1 : (b2 ? x : m2);
                int   ni2 = b1 ? i1 : (b2 ? idx : i2);
                m1 = b1 ? x : m1;
                i1 = b1 ? idx : i1;
                m2 = nm2; i2 = ni2;
            }
        }
    }
    candv[t] = m1; candi[t] = i1;
    if (t == 0) s_cnt = 0;
    __syncthreads();

    // ---- extraction over 512 candidates: 16 rounds -> T = 16th (lex) ----
    int cur = 0;
    for (int round = 0; round < 16; ++round) {
        if (t < 64) {
            float bv = -INFINITY; int bi = 0x7fffffff; int btid = -1;
#pragma unroll
            for (int k2 = 0; k2 < 4; ++k2) {
                int tid = t + 64 * k2;
                float v = candv[tid]; int ii = candi[tid];
                if (vi_better(v, ii, bv, bi)) { bv = v; bi = ii; btid = tid; }
            }
#pragma unroll
            for (int ms = 1; ms < 64; ms <<= 1) {
                float ov = __shfl_xor(bv, ms, 64);
                int   oi = __shfl_xor(bi, ms, 64);
                int   ot = __shfl_xor(btid, ms, 64);
                if (vi_better(ov, oi, bv, bi)) { bv = ov; bi = oi; btid = ot; }
            }
            if (t == 0) { s_topv[round] = bv; s_topi[round] = bi; s_wtid = btid; }
        }
        __syncthreads();
        if (t == s_wtid) {
            ++cur;
            candv[t] = (cur < 2) ? m2 : -INFINITY;
            candi[t] = (cur < 2) ? i2 : 0x7fffffff;
        }
        __syncthreads();
    }

    const float M  = s_topv[0];
    const float Tv = s_topv[15];
    const int   Ti = s_topi[15];

    // ---- pass 2: LSE sum (branchless) + candidate collection ----
    float lsum = 0.f;
    for (int i = 0; i < 32; ++i) {
        int i4 = t + 256 * i;
        if (i4 < VV / 4) {
            float4 xv = lrow4[i4];
            float xs[4] = {xv.x, xv.y, xv.z, xv.w};
#pragma unroll
            for (int cc = 0; cc < 4; ++cc) {
                float x = xs[cc];
                int idx = i4 * 4 + cc;
                lsum += __expf(x - M);
                if (!vi_better(Tv, Ti, x, idx)) {   // (x,idx) >= (Tv,Ti) lex
                    int p = atomicAdd(&s_cnt, 1);
                    if (p < CAP) { s_cv[p] = x; s_ci[p] = idx; }
                }
            }
        }
    }
    s_redv[t] = lsum;
    __syncthreads();
    for (int s = 128; s > 0; s >>= 1) {
        if (t < s) s_redv[t] += s_redv[t + s];
        __syncthreads();
    }
    const float lse = M + logf(s_redv[0]);
    int C = s_cnt; if (C > CAP) C = CAP;
    __syncthreads();

    // ---- final exact top-16 over collected candidates ----
    for (int round = 0; round < 16; ++round) {
        float bv = -INFINITY; int bi = 0x7fffffff; int bp = -1;
        for (int j = t; j < C; j += 256) {
            float v = s_cv[j]; int ii = s_ci[j];
            if (vi_better(v, ii, bv, bi)) { bv = v; bi = ii; bp = j; }
        }
        s_redv[t] = bv; s_redi[t] = bi; s_redp[t] = bp;
        __syncthreads();
        if (t < 64) {
#pragma unroll
            for (int k2 = 1; k2 < 4; ++k2) {
                float v = s_redv[t + 64*k2]; int ii = s_redi[t + 64*k2];
                int pp = s_redp[t + 64*k2];
                if (vi_better(v, ii, bv, bi)) { bv = v; bi = ii; bp = pp; }
            }
#pragma unroll
            for (int ms = 1; ms < 64; ms <<= 1) {
                float ov = __shfl_xor(bv, ms, 64);
                int   oi = __shfl_xor(bi, ms, 64);
                int   op = __shfl_xor(bp, ms, 64);
                if (vi_better(ov, oi, bv, bi)) { bv = ov; bi = oi; bp = op; }
            }
            if (t == 0) {
                s_topv[round] = bv; s_topi[round] = bi;
                if (bp >= 0) { s_cv[bp] = -INFINITY; s_ci[bp] = 0x7fffffff; }
            }
        }
        __syncthreads();
    }

    // ---- epilogue ----
    int lbl = labels[r];
    if (t < 16) {
        actions[r*NA + t] = s_topi[t];
        amask[r*NA + t]   = 1;
        lp[r*NA + t]      = s_topv[t] - lse;
    } else if (t == 16) {
        bool dup = false;
#pragma unroll
        for (int k = 0; k < 16; ++k) dup = dup || (s_topi[k] == lbl);
        actions[r*NA + 16] = dup ? 0 : lbl;
        amask[r*NA + 16]   = dup ? 0 : 1;
        lp[r*NA + 16]      = dup ? 0.f : (lrow[lbl] - lse);
        bool valid = (lbl != -100) && (future_valid[r] != 0);
        rvalid[r] = valid ? 1 : 0;
        if (valid) atomicAdd(validcount, 1);
    }
}

// ---------------------------------------------------------------------------
// Kernel 2: gather embed rows -> bf16 AE (2 rows per 256-thread block)
// ---------------------------------------------------------------------------
__global__ __launch_bounds__(256)
void build_embed_kernel(const float* __restrict__ embed,
                        const int* __restrict__ actions,
                        bf16* __restrict__ AE, int m0)
{
    const int t = threadIdx.x;
    const int ml = blockIdx.x * 2 + (t >> 7);
    const int gm = m0 + ml;
    const int r = gm / NA;
    const int a = gm - r * NA;
    const int tt = t & 127;
    const float* src = embed + (size_t)actions[r*NA + a] * HH + tt * 8;
    float4 v0 = ((const float4*)src)[0];
    float4 v1 = ((const float4*)src)[1];
    bf16x8 o;
    o[0] = (bf16)v0.x; o[1] = (bf16)v0.y; o[2] = (bf16)v0.z; o[3] = (bf16)v0.w;
    o[4] = (bf16)v1.x; o[5] = (bf16)v1.y; o[6] = (bf16)v1.z; o[7] = (bf16)v1.w;
    *(bf16x8*)(AE + (size_t)ml * HH + tt * 8) = o;
}

// ---------------------------------------------------------------------------
// Kernel 3: 128x128 MFMA GEMM, 3-buffer pipelined K-loop (T4 counted vmcnt,
// raw s_barrier — no vmcnt(0) drain mid-loop) + LDS XOR swizzle (T2,
// both-sides: pre-swizzled global source, linear gload_lds dest, swizzled
// ds_read).  XCD-chunked block swizzle.
// C = A(MxK, stride lda) * Bt(NxK, stride ldb, col offset koff)^T
// MODE 0: outF = acc                (GEMM2 -> D f32)
// MODE 1: outB = GELU(acc + Hpre[(m0+m)/NA][n])   (GEMM1' -> Y bf16)
// MODE 2: outF = acc + bias[n]      (Hpre = hidden @ W1_top + b1)
// ---------------------------------------------------------------------------
template<int MODE>
__global__ __launch_bounds__(256, 2)
void gemm128(const bf16* __restrict__ A, int lda,
             const bf16* __restrict__ Bt, int ldb, int koff, int K,
             const float* __restrict__ extra,
             bf16* __restrict__ outB, float* __restrict__ outF,
             int ldo, int nbx, int m0)
{
    const int nwg = gridDim.x;
    const int per = nwg >> 3;
    const int id  = blockIdx.x;
    const int sid = (id & 7) * per + (id >> 3);   // XCD-chunked (bijective)
    const int nb = sid % nbx;
    const int mb = sid / nbx;

    const int t = threadIdx.x;
    const int w = t >> 6, lane = t & 63;
    const int q = lane >> 4, c = lane & 15;
    const int wr = w >> 1, wc = w & 1;

    // 3 buffers x {A,B} x 128x32 bf16 = 48 KB
    __shared__ __align__(16) bf16 sAB[3][2][128 * 32];

    // staging: source lane permutation (involution) so that linear LDS dest +
    // swizzled read = conflict-free.  slot s holds global slot s (swizzled).
    const int sl = (lane & ~3) | ((lane & 3) ^ ((lane >> 3) & 3));
    const int j0 = w * 2, j1 = w * 2 + 1;     // chunks staged by this wave
    const int srow0 = j0 * 16 + (sl >> 2);    // tile-row for chunk j0
    const int srow1 = j1 * 16 + (sl >> 2);
    const int scol  = (sl & 3) * 8;           // k-offset within 32-col tile
    const bf16* gA0 = A  + (size_t)(mb*128 + srow0) * lda + scol;
    const bf16* gA1 = A  + (size_t)(mb*128 + srow1) * lda + scol;
    const bf16* gB0 = Bt + (size_t)(nb*128 + srow0) * ldb + koff + scol;
    const bf16* gB1 = Bt + (size_t)(nb*128 + srow1) * ldb + koff + scol;

    auto STAGE = [&](int b, int kk) {
        gload16(gA0 + kk, &sAB[b][0][j0 * 512]);
        gload16(gA1 + kk, &sAB[b][0][j1 * 512]);
        gload16(gB0 + kk, &sAB[b][1][j0 * 512]);
        gload16(gB1 + kk, &sAB[b][1][j1 * 512]);
    };

    const f32x4 z4 = {0.f, 0.f, 0.f, 0.f};
    f32x4 acc[4][4];
#pragma unroll
    for (int mt = 0; mt < 4; ++mt)
#pragma unroll
        for (int nt = 0; nt < 4; ++nt) acc[mt][nt] = z4;

    const int nk = K >> 5;
    STAGE(0, 0);
    if (nk > 1) STAGE(1, 32);

    // swizzled read slot: within chunk, row_local = c, slot = 4c + (q^((c>>1)&3))
    const int qe = (q ^ ((c >> 1) & 3)) * 8;  // elems

#pragma unroll 1
    for (int i = 0; i < nk; ++i) {
        const int b = i % 3;
        if (i + 2 < nk) STAGE((i + 2) % 3, (i + 2) * 32);

        const int rem = nk - 1 - i;
        if (rem >= 2)      asm volatile("s_waitcnt vmcnt(8)" ::: "memory");
        else if (rem == 1) asm volatile("s_waitcnt vmcnt(4)" ::: "memory");
        else               asm volatile("s_waitcnt vmcnt(0)" ::: "memory");
        __builtin_amdgcn_s_barrier();          // tile i staged by ALL waves
        asm volatile("" ::: "memory");

        const bf16* baseA = &sAB[b][0][0];
        const bf16* baseB = &sAB[b][1][0];
        bf16x8 af[4], bfr[4];
#pragma unroll
        for (int mt = 0; mt < 4; ++mt)
            af[mt] = *(const bf16x8*)&baseA[(wr*4 + mt) * 512 + c * 32 + qe];
#pragma unroll
        for (int nt = 0; nt < 4; ++nt)
            bfr[nt] = *(const bf16x8*)&baseB[(wc*4 + nt) * 512 + c * 32 + qe];
#pragma unroll
        for (int mt = 0; mt < 4; ++mt)
#pragma unroll
            for (int nt = 0; nt < 4; ++nt)
                acc[mt][nt] = mfma16(af[mt], bfr[nt], acc[mt][nt]);

        asm volatile("" ::: "memory");
        __builtin_amdgcn_s_barrier();          // reads of b done before reuse
    }

    const int mrow = mb*128 + wr*64;
    const int ncol = nb*128 + wc*64;
#pragma unroll
    for (int nt = 0; nt < 4; ++nt) {
        const int n = ncol + nt*16 + c;
        float bb = 0.f;
        if constexpr (MODE == 2) bb = extra[n];
#pragma unroll
        for (int mt = 0; mt < 4; ++mt) {
#pragma unroll
            for (int reg = 0; reg < 4; ++reg) {
                const int m = mrow + mt*16 + q*4 + reg;
                float x = acc[mt][nt][reg];
                if constexpr (MODE == 0) {
                    outF[(size_t)m * ldo + n] = x;
                } else if constexpr (MODE == 1) {
                    const int gr = (m0 + m) / NA;
                    x += extra[(size_t)gr * INNER + n];
                    const float g = 0.5f * x * (1.f + erff(x * 0.70710678118654752f));
                    outB[(size_t)m * ldo + n] = (bf16)g;
                } else {
                    outF[(size_t)m * ldo + n] = x + bb;
                }
            }
        }
    }
}

// ---------------------------------------------------------------------------
// Kernel 4: per action-row: +b2, LayerNorm, cosine(action_repr, future) -> score
// ---------------------------------------------------------------------------
__global__ __launch_bounds__(256)
void ln_cos_kernel(const float* __restrict__ D,
                   const float* __restrict__ b2,
                   const float* __restrict__ ln_g,
                   const float* __restrict__ ln_b,
                   const float* __restrict__ future,
                   int m0,
                   float* __restrict__ scores)
{
    const int ml = blockIdx.x;
    const int m = m0 + ml;
    const int r = m / NA;
    const int t = threadIdx.x;
    const int w = t >> 6, lane = t & 63;
    __shared__ float s1[4], s2[4], s3[4], s4[4], s5[4];

    float4 d  = ((const float4*)(D + (size_t)ml * HH))[t];
    float4 bb = ((const float4*)b2)[t];
    d.x += bb.x; d.y += bb.y; d.z += bb.z; d.w += bb.w;

    float p1 = d.x + d.y + d.z + d.w;
    float p2 = d.x*d.x + d.y*d.y + d.z*d.z + d.w*d.w;
#pragma unroll
    for (int m2 = 1; m2 < 64; m2 <<= 1) {
        p1 += __shfl_xor(p1, m2, 64);
        p2 += __shfl_xor(p2, m2, 64);
    }
    if (lane == 0) { s1[w] = p1; s2[w] = p2; }
    __syncthreads();
    const float S1 = s1[0] + s1[1] + s1[2] + s1[3];
    const float S2 = s2[0] + s2[1] + s2[2] + s2[3];
    const float mu = S1 * (1.f / (float)HH);
    const float rstd = rsqrtf(S2 * (1.f / (float)HH) - mu*mu + 1e-5f);

    float4 g = ((const float4*)ln_g)[t];
    float4 b = ((const float4*)ln_b)[t];
    float4 f = ((const float4*)(future + (size_t)r * HH))[t];
    float4 ar;
    ar.x = (d.x - mu) * rstd * g.x + b.x;
    ar.y = (d.y - mu) * rstd * g.y + b.y;
    ar.z = (d.z - mu) * rstd * g.z + b.z;
    ar.w = (d.w - mu) * rstd * g.w + b.w;
    float paa = ar.x*ar.x + ar.y*ar.y + ar.z*ar.z + ar.w*ar.w;
    float paf = ar.x*f.x  + ar.y*f.y  + ar.z*f.z  + ar.w*f.w;
    float pff = f.x*f.x   + f.y*f.y   + f.z*f.z   + f.w*f.w;
#pragma unroll
    for (int m2 = 1; m2 < 64; m2 <<= 1) {
        paa += __shfl_xor(paa, m2, 64);
        paf += __shfl_xor(paf, m2, 64);
        pff += __shfl_xor(pff, m2, 64);
    }
    if (lane == 0) { s3[w] = paa; s4[w] = paf; s5[w] = pff; }
    __syncthreads();
    if (t == 0) {
        const float Saa = s3[0] + s3[1] + s3[2] + s3[3];
        const float Saf = s4[0] + s4[1] + s4[2] + s4[3];
        const float Sff = s5[0] + s5[1] + s5[2] + s5[3];
        const float anorm = fmaxf(sqrtf(Saa), 1e-12f);
        const float fnorm = fmaxf(sqrtf(Sff), 1e-12f);
        scores[m] = Saf / (anorm * fnorm);
    }
}

// ---------------------------------------------------------------------------
// Kernel 5: per token-row softmax over 17 scores + loss accumulation
// ---------------------------------------------------------------------------
__global__ __launch_bounds__(256)
void loss_kernel(const float* __restrict__ scores,
                 const int* __restrict__ amask,
                 const float* __restrict__ lp,
                 const int* __restrict__ rvalid,
                 const int* __restrict__ validcount,
                 float* __restrict__ out)
{
    const int r = blockIdx.x * blockDim.x + threadIdx.x;
    if (r >= BTOT) return;
    float sc[NA];
    float mx = -INFINITY;
#pragma unroll
    for (int a = 0; a < NA; ++a) {
        sc[a] = amask[r*NA + a] ? scores[r*NA + a] : -1e9f;
        mx = fmaxf(mx, sc[a]);
    }
    float ex[NA]; float ses = 0.f;
#pragma unroll
    for (int a = 0; a < NA; ++a) { ex[a] = __expf(sc[a] - mx); ses += ex[a]; }
    const int validr = rvalid[r];
    float acc = 0.f; int denom = 0;
#pragma unroll
    for (int a = 0; a < NA; ++a) {
        const int mk = amask[r*NA + a];
        const int mv = (mk && validr) ? 1 : 0;
        const float rw = (ex[a] / ses) * (float)mk;
        acc += rw * lp[r*NA + a] * (float)mv;
        denom += mv;
    }
    const float lossr = -acc / (float)(denom > 0 ? denom : 1) * (float)validr;
    atomicAdd(out, lossr / fmaxf((float)(*validcount), 1.f));
}

// ---------------------------------------------------------------------------
extern "C" void kernel_launch(void* const* d_in, const int* in_sizes, int n_in,
                              void* d_out, int out_size, void* d_ws, size_t ws_size,
                              hipStream_t stream)
{
    const float* logits        = (const float*)d_in[0];
    const float* hidden        = (const float*)d_in[1];
    const int*   labels        = (const int*)d_in[2];
    const float* future        = (const float*)d_in[3];
    const unsigned char* fvld  = (const unsigned char*)d_in[4];
    const float* embed         = (const float*)d_in[5];
    const float* W1f           = (const float*)d_in[6];
    const float* b1            = (const float*)d_in[7];
    const float* W2f           = (const float*)d_in[8];
    const float* b2            = (const float*)d_in[9];
    const float* ln_g          = (const float*)d_in[10];
    const float* ln_b          = (const float*)d_in[11];
    float* out = (float*)d_out;

    // ws layout: W1T | W2T | hiddenB | Hpre | counters | per-row arrays | slab
    char* ws = (char*)d_ws;
    size_t off = 0;
    bf16*  W1T   = (bf16*)(ws + off);  off += (size_t)INNER * INNER * 2;  // 8 MB
    bf16*  W2T   = (bf16*)(ws + off);  off += (size_t)HH * INNER * 2;     // 4 MB
    bf16*  hidB  = (bf16*)(ws + off);  off += (size_t)BTOT * HH * 2;      // 4 MB
    float* Hpre  = (float*)(ws + off); off += (size_t)BTOT * INNER * 4;   // 16 MB
    int*   validcount = (int*)(ws + off);   off += 256;
    int*   actions    = (int*)(ws + off);   off += (size_t)MTOT * 4;
    int*   amask      = (int*)(ws + off);   off += (size_t)MTOT * 4;
    float* lp         = (float*)(ws + off); off += (size_t)MTOT * 4;
    int*   rvalid     = (int*)(ws + off);   off += (size_t)BTOT * 4;
    float* scores     = (float*)(ws + off); off += (size_t)MTOT * 4;
    off = (off + 255) & ~(size_t)255;

    // slab per 128-row block: AE bf16 (256KB) + Y bf16 (512KB) + D f32 (512KB)
    size_t rem = (ws_size > off) ? (ws_size - off) : 0;
    long long cap_blocks = (long long)(rem / ((size_t)10240 * 128));
    int slab_blocks = (cap_blocks > (MTOT/128)) ? (MTOT/128) : (int)cap_blocks;
    if (slab_blocks < 1) slab_blocks = 1;
    const int slab_rows_max = slab_blocks * 128;

    bf16*  AEbuf = (bf16*)(ws + off);
    bf16*  Ybuf  = (bf16*)(ws + off + (size_t)slab_rows_max * 2048);
    float* Dbuf  = (float*)(ws + off + (size_t)slab_rows_max * (2048 + 4096));

    (void)hipMemsetAsync(d_out, 0, sizeof(float), stream);
    (void)hipMemsetAsync(validcount, 0, 16, stream);

    transpose_to_bf16<<<dim3(INNER/32, INNER/32), dim3(32, 8), 0, stream>>>(W1f, W1T, INNER, INNER);
    transpose_to_bf16<<<dim3(HH/32,    INNER/32), dim3(32, 8), 0, stream>>>(W2f, W2T, INNER, HH);
    cast_hidden_kernel<<<(BTOT*HH)/2048, 256, 0, stream>>>(hidden, hidB);

    // Hpre = hidden @ W1_top + b1   (M=2048, N=2048, K=1024)
    gemm128<2><<<(INNER/128) * (BTOT/128), 256, 0, stream>>>(
        hidB, HH, W1T, INNER, 0, HH, b1, nullptr, Hpre, INNER, INNER/128, 0);

    topk_lse_kernel<<<BTOT, 256, 0, stream>>>(logits, labels, fvld,
                                              actions, amask, lp, rvalid, validcount);

    for (int m0 = 0; m0 < MTOT; m0 += slab_rows_max) {
        const int rows = (MTOT - m0 < slab_rows_max) ? (MTOT - m0) : slab_rows_max;
        const int nbm = rows / 128;
        build_embed_kernel<<<rows/2, 256, 0, stream>>>(embed, actions, AEbuf, m0);
        // Y = GELU(AE @ W1_bot + Hpre[row])   (N=2048, K=1024, koff=1024)
        gemm128<1><<<(INNER/128) * nbm, 256, 0, stream>>>(
            AEbuf, HH, W1T, INNER, HH, HH, Hpre, Ybuf, nullptr, INNER, INNER/128, m0);
        // D = Y @ W2T                          (N=1024, K=2048)
        gemm128<0><<<(HH/128) * nbm, 256, 0, stream>>>(
            Ybuf, INNER, W2T, INNER, 0, INNER, nullptr, nullptr, Dbuf, HH, HH/128, 0);
        ln_cos_kernel<<<rows, 256, 0, stream>>>(Dbuf, b2, ln_g, ln_b, future, m0, scores);
    }

    loss_kernel<<<(BTOT + 255) / 256, 256, 0, stream>>>(scores, amask, lp,
                                                        rvalid, validcount, out);
}

// Round 7
// 1081.871 us; speedup vs baseline: 7.7301x; 1.0083x over previous
//
#include <hip/hip_runtime.h>
#include <hip/hip_bf16.h>
#include <math.h>

#define BTOT 2048
#define VV 32000
#define HH 1024
#define INNER 2048
#define NA 17
#define MTOT (BTOT * NA)   // 34816 action-rows = 272 * 128
#define CAP 1088           // candidate buffer (provable worst case <= 1024)

typedef __bf16 bf16;
typedef __bf16 bf16x8 __attribute__((ext_vector_type(8)));
typedef float f32x4 __attribute__((ext_vector_type(4)));

__device__ __forceinline__ f32x4 mfma16(bf16x8 a, bf16x8 b, f32x4 c) {
    return __builtin_amdgcn_mfma_f32_16x16x32_bf16(a, b, c, 0, 0, 0);
}

// async global->LDS, 16B per lane; LDS dest is wave-uniform base + lane*16
__device__ __forceinline__ void gload16(const void* g, void* l) {
    __builtin_amdgcn_global_load_lds(
        (const __attribute__((address_space(1))) unsigned int*)g,
        (__attribute__((address_space(3))) unsigned int*)l, 16, 0, 0);
}

__device__ __forceinline__ bool vi_better(float va, int ia, float vb, int ib) {
    // jax.lax.top_k order: larger value first; ties -> smaller index first
    return (va > vb) || (va == vb && ia < ib);
}

// ---------------------------------------------------------------------------
// Kernel 0: tiled transpose f32 -> bf16.  dst[c][r] = (bf16)src[r][c]
// ---------------------------------------------------------------------------
__global__ __launch_bounds__(256)
void transpose_to_bf16(const float* __restrict__ src, bf16* __restrict__ dst,
                       int R, int C)
{
    __shared__ float tile[32][33];
    const int bx = blockIdx.x * 32;
    const int by = blockIdx.y * 32;
    const int tx = threadIdx.x;
    const int ty = threadIdx.y;
#pragma unroll
    for (int i = 0; i < 32; i += 8)
        tile[ty + i][tx] = src[(size_t)(by + ty + i) * C + bx + tx];
    __syncthreads();
#pragma unroll
    for (int i = 0; i < 32; i += 8)
        dst[(size_t)(bx + ty + i) * R + by + tx] = (bf16)tile[tx][ty + i];
}

// ---------------------------------------------------------------------------
// Kernel 0b: cast hidden f32 -> bf16 (2048 x 1024)
// ---------------------------------------------------------------------------
__global__ __launch_bounds__(256)
void cast_hidden_kernel(const float* __restrict__ hidden, bf16* __restrict__ hb)
{
    const size_t i = ((size_t)blockIdx.x * 256 + threadIdx.x) * 8;
    float4 v0 = ((const float4*)(hidden + i))[0];
    float4 v1 = ((const float4*)(hidden + i))[1];
    bf16x8 o;
    o[0] = (bf16)v0.x; o[1] = (bf16)v0.y; o[2] = (bf16)v0.z; o[3] = (bf16)v0.w;
    o[4] = (bf16)v1.x; o[5] = (bf16)v1.y; o[6] = (bf16)v1.z; o[7] = (bf16)v1.w;
    *(bf16x8*)(hb + i) = o;
}

// ---------------------------------------------------------------------------
// Kernel 1: per-row top-16 + LSE, two-pass threshold select (unchanged)
// ---------------------------------------------------------------------------
__global__ __launch_bounds__(256)
void topk_lse_kernel(const float* __restrict__ logits,
                     const int* __restrict__ labels,
                     const unsigned char* __restrict__ future_valid,
                     int* __restrict__ actions,
                     int* __restrict__ amask,
                     float* __restrict__ lp,
                     int* __restrict__ rvalid,
                     int* __restrict__ validcount)
{
    const int r = blockIdx.x;
    const int t = threadIdx.x;
    const float* __restrict__ lrow = logits + (size_t)r * VV;

    __shared__ float s_cv[CAP];
    __shared__ int   s_ci[CAP];
    __shared__ float candv[256];
    __shared__ int   candi[256];
    __shared__ float s_topv[16];
    __shared__ int   s_topi[16];
    __shared__ int   s_wtid;
    __shared__ int   s_cnt;
    __shared__ float s_redv[256];
    __shared__ int   s_redi[256];
    __shared__ int   s_redp[256];

    // ---- pass 1: per-thread top-2 (branchless) ----
    float m1 = -INFINITY, m2 = -INFINITY;
    int   i1 = 0x7fffffff, i2 = 0x7fffffff;
    const float4* __restrict__ lrow4 = (const float4*)lrow;
    for (int i = 0; i < 32; ++i) {
        int i4 = t + 256 * i;
        if (i4 < VV / 4) {
            float4 xv = lrow4[i4];
            float xs[4] = {xv.x, xv.y, xv.z, xv.w};
#pragma unroll
            for (int cc = 0; cc < 4; ++cc) {
                float x = xs[cc];
                int idx = i4 * 4 + cc;
                bool b1 = x > m1;
                bool b2 = x > m2;
                float nm2 = b1 ? m1 : (b2 ? x : m2);
                int   ni2 = b1 ? i1 : (b2 ? idx : i2);
                m1 = b1 ? x : m1;
                i1 = b1 ? idx : i1;
                m2 = nm2; i2 = ni2;
            }
        }
    }
    candv[t] = m1; candi[t] = i1;
    if (t == 0) s_cnt = 0;
    __syncthreads();

    // ---- extraction over 512 candidates: 16 rounds -> T = 16th (lex) ----
    int cur = 0;
    for (int round = 0; round < 16; ++round) {
        if (t < 64) {
            float bv = -INFINITY; int bi = 0x7fffffff; int btid = -1;
#pragma unroll
            for (int k2 = 0; k2 < 4; ++k2) {
                int tid = t + 64 * k2;
                float v = candv[tid]; int ii = candi[tid];
                if (vi_better(v, ii, bv, bi)) { bv = v; bi = ii; btid = tid; }
            }
#pragma unroll
            for (int ms = 1; ms < 64; ms <<= 1) {
                float ov = __shfl_xor(bv, ms, 64);
                int   oi = __shfl_xor(bi, ms, 64);
                int   ot = __shfl_xor(btid, ms, 64);
                if (vi_better(ov, oi, bv, bi)) { bv = ov; bi = oi; btid = ot; }
            }
            if (t == 0) { s_topv[round] = bv; s_topi[round] = bi; s_wtid = btid; }
        }
        __syncthreads();
        if (t == s_wtid) {
            ++cur;
            candv[t] = (cur < 2) ? m2 : -INFINITY;
            candi[t] = (cur < 2) ? i2 : 0x7fffffff;
        }
        __syncthreads();
    }

    const float M  = s_topv[0];
    const float Tv = s_topv[15];
    const int   Ti = s_topi[15];

    // ---- pass 2: LSE sum (branchless) + candidate collection ----
    float lsum = 0.f;
    for (int i = 0; i < 32; ++i) {
        int i4 = t + 256 * i;
        if (i4 < VV / 4) {
            float4 xv = lrow4[i4];
            float xs[4] = {xv.x, xv.y, xv.z, xv.w};
#pragma unroll
            for (int cc = 0; cc < 4; ++cc) {
                float x = xs[cc];
                int idx = i4 * 4 + cc;
                lsum += __expf(x - M);
                if (!vi_better(Tv, Ti, x, idx)) {   // (x,idx) >= (Tv,Ti) lex
                    int p = atomicAdd(&s_cnt, 1);
                    if (p < CAP) { s_cv[p] = x; s_ci[p] = idx; }
                }
            }
        }
    }
    s_redv[t] = lsum;
    __syncthreads();
    for (int s = 128; s > 0; s >>= 1) {
        if (t < s) s_redv[t] += s_redv[t + s];
        __syncthreads();
    }
    const float lse = M + logf(s_redv[0]);
    int C = s_cnt; if (C > CAP) C = CAP;
    __syncthreads();

    // ---- final exact top-16 over collected candidates ----
    for (int round = 0; round < 16; ++round) {
        float bv = -INFINITY; int bi = 0x7fffffff; int bp = -1;
        for (int j = t; j < C; j += 256) {
            float v = s_cv[j]; int ii = s_ci[j];
            if (vi_better(v, ii, bv, bi)) { bv = v; bi = ii; bp = j; }
        }
        s_redv[t] = bv; s_redi[t] = bi; s_redp[t] = bp;
        __syncthreads();
        if (t < 64) {
#pragma unroll
            for (int k2 = 1; k2 < 4; ++k2) {
                float v = s_redv[t + 64*k2]; int ii = s_redi[t + 64*k2];
                int pp = s_redp[t + 64*k2];
                if (vi_better(v, ii, bv, bi)) { bv = v; bi = ii; bp = pp; }
            }
#pragma unroll
            for (int ms = 1; ms < 64; ms <<= 1) {
                float ov = __shfl_xor(bv, ms, 64);
                int   oi = __shfl_xor(bi, ms, 64);
                int   op = __shfl_xor(bp, ms, 64);
                if (vi_better(ov, oi, bv, bi)) { bv = ov; bi = oi; bp = op; }
            }
            if (t == 0) {
                s_topv[round] = bv; s_topi[round] = bi;
                if (bp >= 0) { s_cv[bp] = -INFINITY; s_ci[bp] = 0x7fffffff; }
            }
        }
        __syncthreads();
    }

    // ---- epilogue ----
    int lbl = labels[r];
    if (t < 16) {
        actions[r*NA + t] = s_topi[t];
        amask[r*NA + t]   = 1;
        lp[r*NA + t]      = s_topv[t] - lse;
    } else if (t == 16) {
        bool dup = false;
#pragma unroll
        for (int k = 0; k < 16; ++k) dup = dup || (s_topi[k] == lbl);
        actions[r*NA + 16] = dup ? 0 : lbl;
        amask[r*NA + 16]   = dup ? 0 : 1;
        lp[r*NA + 16]      = dup ? 0.f : (lrow[lbl] - lse);
        bool valid = (lbl != -100) && (future_valid[r] != 0);
        rvalid[r] = valid ? 1 : 0;
        if (valid) atomicAdd(validcount, 1);
    }
}

// ---------------------------------------------------------------------------
// Kernel 2: gather embed rows -> bf16 AE (2 rows per 256-thread block)
// ---------------------------------------------------------------------------
__global__ __launch_bounds__(256)
void build_embed_kernel(const float* __restrict__ embed,
                        const int* __restrict__ actions,
                        bf16* __restrict__ AE, int m0)
{
    const int t = threadIdx.x;
    const int ml = blockIdx.x * 2 + (t >> 7);
    const int gm = m0 + ml;
    const int r = gm / NA;
    const int a = gm - r * NA;
    const int tt = t & 127;
    const float* src = embed + (size_t)actions[r*NA + a] * HH + tt * 8;
    float4 v0 = ((const float4*)src)[0];
    float4 v1 = ((const float4*)src)[1];
    bf16x8 o;
    o[0] = (bf16)v0.x; o[1] = (bf16)v0.y; o[2] = (bf16)v0.z; o[3] = (bf16)v0.w;
    o[4] = (bf16)v1.x; o[5] = (bf16)v1.y; o[6] = (bf16)v1.z; o[7] = (bf16)v1.w;
    *(bf16x8*)(AE + (size_t)ml * HH + tt * 8) = o;
}

// ---------------------------------------------------------------------------
// Kernel 3: 128x128 MFMA GEMM, 2-buffer 2-phase K-loop (T3/T4 minimum recipe:
// STAGE(next) issued BEFORE compute; ONE vmcnt(0)+s_barrier per k-step, placed
// after MFMA so the prefetch wait is covered by compute).  LDS 32 KB ->
// 5 blocks/CU.  LDS XOR swizzle kept (bank-conflict 0, verified r6).
// XCD-chunked block swizzle.
// C = A(MxK, stride lda) * Bt(NxK, stride ldb, col offset koff)^T
// MODE 0: outF = acc                (GEMM2 -> D f32)
// MODE 1: outB = GELU(acc + Hpre[(m0+m)/NA][n])   (GEMM1' -> Y bf16)
// MODE 2: outF = acc + bias[n]      (Hpre = hidden @ W1_top + b1)
// ---------------------------------------------------------------------------
template<int MODE>
__global__ __launch_bounds__(256, 4)
void gemm128(const bf16* __restrict__ A, int lda,
             const bf16* __restrict__ Bt, int ldb, int koff, int K,
             const float* __restrict__ extra,
             bf16* __restrict__ outB, float* __restrict__ outF,
             int ldo, int nbx, int m0)
{
    const int nwg = gridDim.x;
    const int per = nwg >> 3;
    const int id  = blockIdx.x;
    const int sid = (id & 7) * per + (id >> 3);   // XCD-chunked (bijective)
    const int nb = sid % nbx;
    const int mb = sid / nbx;

    const int t = threadIdx.x;
    const int w = t >> 6, lane = t & 63;
    const int q = lane >> 4, c = lane & 15;
    const int wr = w >> 1, wc = w & 1;

    // 2 buffers x {A,B} x 128x32 bf16 = 32 KB  -> 5 blocks/CU
    __shared__ __align__(16) bf16 sAB[2][2][128 * 32];

    // staging: source lane permutation (involution) so that linear LDS dest +
    // swizzled read = conflict-free.
    const int sl = (lane & ~3) | ((lane & 3) ^ ((lane >> 3) & 3));
    const int j0 = w * 2, j1 = w * 2 + 1;     // chunks staged by this wave
    const int srow0 = j0 * 16 + (sl >> 2);
    const int srow1 = j1 * 16 + (sl >> 2);
    const int scol  = (sl & 3) * 8;
    const bf16* gA0 = A  + (size_t)(mb*128 + srow0) * lda + scol;
    const bf16* gA1 = A  + (size_t)(mb*128 + srow1) * lda + scol;
    const bf16* gB0 = Bt + (size_t)(nb*128 + srow0) * ldb + koff + scol;
    const bf16* gB1 = Bt + (size_t)(nb*128 + srow1) * ldb + koff + scol;

    auto STAGE = [&](int b, int kk) {
        gload16(gA0 + kk, &sAB[b][0][j0 * 512]);
        gload16(gA1 + kk, &sAB[b][0][j1 * 512]);
        gload16(gB0 + kk, &sAB[b][1][j0 * 512]);
        gload16(gB1 + kk, &sAB[b][1][j1 * 512]);
    };

    const f32x4 z4 = {0.f, 0.f, 0.f, 0.f};
    f32x4 acc[4][4];
#pragma unroll
    for (int mt = 0; mt < 4; ++mt)
#pragma unroll
        for (int nt = 0; nt < 4; ++nt) acc[mt][nt] = z4;

    const int nk = K >> 5;

    // prologue: stage tile 0, wait, barrier
    STAGE(0, 0);
    asm volatile("s_waitcnt vmcnt(0)" ::: "memory");
    __builtin_amdgcn_s_barrier();

    // swizzled read slot: slot = 4c + (q^((c>>1)&3))
    const int qe = (q ^ ((c >> 1) & 3)) * 8;  // elems

    int cur = 0;
#pragma unroll 1
    for (int i = 0; i < nk; ++i) {
        if (i + 1 < nk) STAGE(cur ^ 1, (i + 1) * 32);   // prefetch next tile

        const bf16* baseA = &sAB[cur][0][0];
        const bf16* baseB = &sAB[cur][1][0];
        bf16x8 af[4], bfr[4];
#pragma unroll
        for (int mt = 0; mt < 4; ++mt)
            af[mt] = *(const bf16x8*)&baseA[(wr*4 + mt) * 512 + c * 32 + qe];
#pragma unroll
        for (int nt = 0; nt < 4; ++nt)
            bfr[nt] = *(const bf16x8*)&baseB[(wc*4 + nt) * 512 + c * 32 + qe];
#pragma unroll
        for (int mt = 0; mt < 4; ++mt)
#pragma unroll
            for (int nt = 0; nt < 4; ++nt)
                acc[mt][nt] = mfma16(af[mt], bfr[nt], acc[mt][nt]);

        if (i + 1 < nk) {
            // next tile's loads were issued ~compute-time ago: wait is cheap.
            // barrier also proves all waves done reading buf cur (reads
            // completed before their MFMAs) -> safe to overwrite next iter.
            asm volatile("s_waitcnt vmcnt(0)" ::: "memory");
            __builtin_amdgcn_s_barrier();
        }
        cur ^= 1;
    }

    const int mrow = mb*128 + wr*64;
    const int ncol = nb*128 + wc*64;
#pragma unroll
    for (int nt = 0; nt < 4; ++nt) {
        const int n = ncol + nt*16 + c;
        float bb = 0.f;
        if constexpr (MODE == 2) bb = extra[n];
#pragma unroll
        for (int mt = 0; mt < 4; ++mt) {
#pragma unroll
            for (int reg = 0; reg < 4; ++reg) {
                const int m = mrow + mt*16 + q*4 + reg;
                float x = acc[mt][nt][reg];
                if constexpr (MODE == 0) {
                    outF[(size_t)m * ldo + n] = x;
                } else if constexpr (MODE == 1) {
                    const int gr = (m0 + m) / NA;
                    x += extra[(size_t)gr * INNER + n];
                    const float g = 0.5f * x * (1.f + erff(x * 0.70710678118654752f));
                    outB[(size_t)m * ldo + n] = (bf16)g;
                } else {
                    outF[(size_t)m * ldo + n] = x + bb;
                }
            }
        }
    }
}

// ---------------------------------------------------------------------------
// Kernel 4: per action-row: +b2, LayerNorm, cosine(action_repr, future) -> score
// ---------------------------------------------------------------------------
__global__ __launch_bounds__(256)
void ln_cos_kernel(const float* __restrict__ D,
                   const float* __restrict__ b2,
                   const float* __restrict__ ln_g,
                   const float* __restrict__ ln_b,
                   const float* __restrict__ future,
                   int m0,
                   float* __restrict__ scores)
{
    const int ml = blockIdx.x;
    const int m = m0 + ml;
    const int r = m / NA;
    const int t = threadIdx.x;
    const int w = t >> 6, lane = t & 63;
    __shared__ float s1[4], s2[4], s3[4], s4[4], s5[4];

    float4 d  = ((const float4*)(D + (size_t)ml * HH))[t];
    float4 bb = ((const float4*)b2)[t];
    d.x += bb.x; d.y += bb.y; d.z += bb.z; d.w += bb.w;

    float p1 = d.x + d.y + d.z + d.w;
    float p2 = d.x*d.x + d.y*d.y + d.z*d.z + d.w*d.w;
#pragma unroll
    for (int m2 = 1; m2 < 64; m2 <<= 1) {
        p1 += __shfl_xor(p1, m2, 64);
        p2 += __shfl_xor(p2, m2, 64);
    }
    if (lane == 0) { s1[w] = p1; s2[w] = p2; }
    __syncthreads();
    const float S1 = s1[0] + s1[1] + s1[2] + s1[3];
    const float S2 = s2[0] + s2[1] + s2[2] + s2[3];
    const float mu = S1 * (1.f / (float)HH);
    const float rstd = rsqrtf(S2 * (1.f / (float)HH) - mu*mu + 1e-5f);

    float4 g = ((const float4*)ln_g)[t];
    float4 b = ((const float4*)ln_b)[t];
    float4 f = ((const float4*)(future + (size_t)r * HH))[t];
    float4 ar;
    ar.x = (d.x - mu) * rstd * g.x + b.x;
    ar.y = (d.y - mu) * rstd * g.y + b.y;
    ar.z = (d.z - mu) * rstd * g.z + b.z;
    ar.w = (d.w - mu) * rstd * g.w + b.w;
    float paa = ar.x*ar.x + ar.y*ar.y + ar.z*ar.z + ar.w*ar.w;
    float paf = ar.x*f.x  + ar.y*f.y  + ar.z*f.z  + ar.w*f.w;
    float pff = f.x*f.x   + f.y*f.y   + f.z*f.z   + f.w*f.w;
#pragma unroll
    for (int m2 = 1; m2 < 64; m2 <<= 1) {
        paa += __shfl_xor(paa, m2, 64);
        paf += __shfl_xor(paf, m2, 64);
        pff += __shfl_xor(pff, m2, 64);
    }
    if (lane == 0) { s3[w] = paa; s4[w] = paf; s5[w] = pff; }
    __syncthreads();
    if (t == 0) {
        const float Saa = s3[0] + s3[1] + s3[2] + s3[3];
        const float Saf = s4[0] + s4[1] + s4[2] + s4[3];
        const float Sff = s5[0] + s5[1] + s5[2] + s5[3];
        const float anorm = fmaxf(sqrtf(Saa), 1e-12f);
        const float fnorm = fmaxf(sqrtf(Sff), 1e-12f);
        scores[m] = Saf / (anorm * fnorm);
    }
}

// ---------------------------------------------------------------------------
// Kernel 5: per token-row softmax over 17 scores + loss accumulation
// ---------------------------------------------------------------------------
__global__ __launch_bounds__(256)
void loss_kernel(const float* __restrict__ scores,
                 const int* __restrict__ amask,
                 const float* __restrict__ lp,
                 const int* __restrict__ rvalid,
                 const int* __restrict__ validcount,
                 float* __restrict__ out)
{
    const int r = blockIdx.x * blockDim.x + threadIdx.x;
    if (r >= BTOT) return;
    float sc[NA];
    float mx = -INFINITY;
#pragma unroll
    for (int a = 0; a < NA; ++a) {
        sc[a] = amask[r*NA + a] ? scores[r*NA + a] : -1e9f;
        mx = fmaxf(mx, sc[a]);
    }
    float ex[NA]; float ses = 0.f;
#pragma unroll
    for (int a = 0; a < NA; ++a) { ex[a] = __expf(sc[a] - mx); ses += ex[a]; }
    const int validr = rvalid[r];
    float acc = 0.f; int denom = 0;
#pragma unroll
    for (int a = 0; a < NA; ++a) {
        const int mk = amask[r*NA + a];
        const int mv = (mk && validr) ? 1 : 0;
        const float rw = (ex[a] / ses) * (float)mk;
        acc += rw * lp[r*NA + a] * (float)mv;
        denom += mv;
    }
    const float lossr = -acc / (float)(denom > 0 ? denom : 1) * (float)validr;
    atomicAdd(out, lossr / fmaxf((float)(*validcount), 1.f));
}

// ---------------------------------------------------------------------------
extern "C" void kernel_launch(void* const* d_in, const int* in_sizes, int n_in,
                              void* d_out, int out_size, void* d_ws, size_t ws_size,
                              hipStream_t stream)
{
    const float* logits        = (const float*)d_in[0];
    const float* hidden        = (const float*)d_in[1];
    const int*   labels        = (const int*)d_in[2];
    const float* future        = (const float*)d_in[3];
    const unsigned char* fvld  = (const unsigned char*)d_in[4];
    const float* embed         = (const float*)d_in[5];
    const float* W1f           = (const float*)d_in[6];
    const float* b1            = (const float*)d_in[7];
    const float* W2f           = (const float*)d_in[8];
    const float* b2            = (const float*)d_in[9];
    const float* ln_g          = (const float*)d_in[10];
    const float* ln_b          = (const float*)d_in[11];
    float* out = (float*)d_out;

    // ws layout: W1T | W2T | hiddenB | Hpre | counters | per-row arrays | slab
    char* ws = (char*)d_ws;
    size_t off = 0;
    bf16*  W1T   = (bf16*)(ws + off);  off += (size_t)INNER * INNER * 2;  // 8 MB
    bf16*  W2T   = (bf16*)(ws + off);  off += (size_t)HH * INNER * 2;     // 4 MB
    bf16*  hidB  = (bf16*)(ws + off);  off += (size_t)BTOT * HH * 2;      // 4 MB
    float* Hpre  = (float*)(ws + off); off += (size_t)BTOT * INNER * 4;   // 16 MB
    int*   validcount = (int*)(ws + off);   off += 256;
    int*   actions    = (int*)(ws + off);   off += (size_t)MTOT * 4;
    int*   amask      = (int*)(ws + off);   off += (size_t)MTOT * 4;
    float* lp         = (float*)(ws + off); off += (size_t)MTOT * 4;
    int*   rvalid     = (int*)(ws + off);   off += (size_t)BTOT * 4;
    float* scores     = (float*)(ws + off); off += (size_t)MTOT * 4;
    off = (off + 255) & ~(size_t)255;

    // slab per 128-row block: AE bf16 (256KB) + Y bf16 (512KB) + D f32 (512KB)
    size_t rem = (ws_size > off) ? (ws_size - off) : 0;
    long long cap_blocks = (long long)(rem / ((size_t)10240 * 128));
    int slab_blocks = (cap_blocks > (MTOT/128)) ? (MTOT/128) : (int)cap_blocks;
    if (slab_blocks < 1) slab_blocks = 1;
    const int slab_rows_max = slab_blocks * 128;

    bf16*  AEbuf = (bf16*)(ws + off);
    bf16*  Ybuf  = (bf16*)(ws + off + (size_t)slab_rows_max * 2048);
    float* Dbuf  = (float*)(ws + off + (size_t)slab_rows_max * (2048 + 4096));

    (void)hipMemsetAsync(d_out, 0, sizeof(float), stream);
    (void)hipMemsetAsync(validcount, 0, 16, stream);

    transpose_to_bf16<<<dim3(INNER/32, INNER/32), dim3(32, 8), 0, stream>>>(W1f, W1T, INNER, INNER);
    transpose_to_bf16<<<dim3(HH/32,    INNER/32), dim3(32, 8), 0, stream>>>(W2f, W2T, INNER, HH);
    cast_hidden_kernel<<<(BTOT*HH)/2048, 256, 0, stream>>>(hidden, hidB);

    // Hpre = hidden @ W1_top + b1   (M=2048, N=2048, K=1024)
    gemm128<2><<<(INNER/128) * (BTOT/128), 256, 0, stream>>>(
        hidB, HH, W1T, INNER, 0, HH, b1, nullptr, Hpre, INNER, INNER/128, 0);

    topk_lse_kernel<<<BTOT, 256, 0, stream>>>(logits, labels, fvld,
                                              actions, amask, lp, rvalid, validcount);

    for (int m0 = 0; m0 < MTOT; m0 += slab_rows_max) {
        const int rows = (MTOT - m0 < slab_rows_max) ? (MTOT - m0) : slab_rows_max;
        const int nbm = rows / 128;
        build_embed_kernel<<<rows/2, 256, 0, stream>>>(embed, actions, AEbuf, m0);
        // Y = GELU(AE @ W1_bot + Hpre[row])   (N=2048, K=1024, koff=1024)
        gemm128<1><<<(INNER/128) * nbm, 256, 0, stream>>>(
            AEbuf, HH, W1T, INNER, HH, HH, Hpre, Ybuf, nullptr, INNER, INNER/128, m0);
        // D = Y @ W2T                          (N=1024, K=2048)
        gemm128<0><<<(HH/128) * nbm, 256, 0, stream>>>(
            Ybuf, INNER, W2T, INNER, 0, INNER, nullptr, nullptr, Dbuf, HH, HH/128, 0);
        ln_cos_kernel<<<rows, 256, 0, stream>>>(Dbuf, b2, ln_g, ln_b, future, m0, scores);
    }

    loss_kernel<<<(BTOT + 255) / 256, 256, 0, stream>>>(scores, amask, lp,
                                                        rvalid, validcount, out);
}